// Round 1
// baseline (12188.613 us; speedup 1.0000x reference)
//
#include <hip/hip_runtime.h>

#define NUM_USERS 100000
#define NUM_ITEMS 50000
#define EMBED_DIM 64
#define N_NODES   (NUM_USERS + NUM_ITEMS)      // 150000
#define N_EDGES   4800000
#define N_LAYERS  3
#define N_QUERY   16384

#define NODE_FLOATS ((size_t)N_NODES * EMBED_DIM)   // 9,600,000
#define NODE_FLOAT4 (NODE_FLOATS / 4)                // 2,400,000

// ---------------------------------------------------------------------------
// init: acc = h = ego = concat(user_emb, item_emb), float4 granularity
// ---------------------------------------------------------------------------
__global__ void init_kernel(const float4* __restrict__ ue4,
                            const float4* __restrict__ ie4,
                            float4* __restrict__ acc,
                            float4* __restrict__ h) {
    size_t i = (size_t)blockIdx.x * blockDim.x + threadIdx.x;
    if (i >= NODE_FLOAT4) return;
    const size_t user_f4 = (size_t)NUM_USERS * EMBED_DIM / 4;  // 1,600,000
    float4 v = (i < user_f4) ? ue4[i] : ie4[i - user_f4];
    acc[i] = v;
    h[i]   = v;
}

// ---------------------------------------------------------------------------
// SpMM: h_next[rows[e]] += vals[e] * h[cols[e]]
// 16 lanes per edge, each lane handles 4 contiguous dims via float4 gather
// and 4 scalar atomicAdds.
// ---------------------------------------------------------------------------
__global__ void spmm_kernel(const int* __restrict__ rows,
                            const int* __restrict__ cols,
                            const float* __restrict__ vals,
                            const float* __restrict__ h,
                            float* __restrict__ hn) {
    size_t idx = (size_t)blockIdx.x * blockDim.x + threadIdx.x;
    size_t e   = idx >> 4;          // edge index
    int    sub = (int)(idx & 15);   // 0..15, 4 dims each
    if (e >= N_EDGES) return;

    int   r = rows[e];
    int   c = cols[e];
    float v = vals[e];

    const float4* src = reinterpret_cast<const float4*>(h + (size_t)c * EMBED_DIM);
    float4 x = src[sub];

    float* dst = hn + (size_t)r * EMBED_DIM + sub * 4;
    atomicAdd(dst + 0, v * x.x);
    atomicAdd(dst + 1, v * x.y);
    atomicAdd(dst + 2, v * x.z);
    atomicAdd(dst + 3, v * x.w);
}

// ---------------------------------------------------------------------------
// acc += hn  (float4)
// ---------------------------------------------------------------------------
__global__ void acc_add_kernel(float4* __restrict__ acc,
                               const float4* __restrict__ hn) {
    size_t i = (size_t)blockIdx.x * blockDim.x + threadIdx.x;
    if (i >= NODE_FLOAT4) return;
    float4 a = acc[i];
    float4 b = hn[i];
    a.x += b.x; a.y += b.y; a.z += b.z; a.w += b.w;
    acc[i] = a;
}

// ---------------------------------------------------------------------------
// out[q] = dot(acc[users[q]], acc[NUM_USERS + items[q]]) / 16
// one 64-lane wave per query, lane d owns dim d
// ---------------------------------------------------------------------------
__global__ void dot_kernel(const int* __restrict__ users,
                           const int* __restrict__ items,
                           const float* __restrict__ acc,
                           float* __restrict__ out) {
    int lane = threadIdx.x & 63;
    int wave = threadIdx.x >> 6;
    int q    = blockIdx.x * (blockDim.x >> 6) + wave;
    if (q >= N_QUERY) return;

    int u = users[q];
    int it = items[q];

    float a = acc[(size_t)u * EMBED_DIM + lane];
    float b = acc[((size_t)NUM_USERS + it) * EMBED_DIM + lane];
    float p = a * b;

    // 64-lane butterfly reduce
    #pragma unroll
    for (int off = 32; off >= 1; off >>= 1)
        p += __shfl_xor(p, off, 64);

    if (lane == 0)
        out[q] = p * (1.0f / 16.0f);   // (acc/4)·(acc/4)
}

// ---------------------------------------------------------------------------
extern "C" void kernel_launch(void* const* d_in, const int* in_sizes, int n_in,
                              void* d_out, int out_size, void* d_ws, size_t ws_size,
                              hipStream_t stream) {
    const int*   users = (const int*)  d_in[0];
    const int*   items = (const int*)  d_in[1];
    const float* ue    = (const float*)d_in[2];
    const float* ie    = (const float*)d_in[3];
    const int*   rows  = (const int*)  d_in[4];
    const int*   cols  = (const int*)  d_in[5];
    const float* vals  = (const float*)d_in[6];
    float*       out   = (float*)d_out;

    float* acc = (float*)d_ws;
    float* h   = acc + NODE_FLOATS;
    float* hn  = h   + NODE_FLOATS;

    // init acc = h = ego
    {
        int blocks = (int)((NODE_FLOAT4 + 255) / 256);
        init_kernel<<<blocks, 256, 0, stream>>>(
            (const float4*)ue, (const float4*)ie, (float4*)acc, (float4*)h);
    }

    int spmm_blocks = (int)(((size_t)N_EDGES * 16 + 255) / 256);
    int vec_blocks  = (int)((NODE_FLOAT4 + 255) / 256);

    float* cur  = h;
    float* next = hn;
    for (int layer = 0; layer < N_LAYERS; ++layer) {
        hipMemsetAsync(next, 0, NODE_FLOATS * sizeof(float), stream);
        spmm_kernel<<<spmm_blocks, 256, 0, stream>>>(rows, cols, vals, cur, next);
        acc_add_kernel<<<vec_blocks, 256, 0, stream>>>((float4*)acc, (const float4*)next);
        float* t = cur; cur = next; next = t;
    }

    // 4 queries (waves) per 256-thread block
    dot_kernel<<<(N_QUERY + 3) / 4, 256, 0, stream>>>(users, items, acc, out);
}

// Round 2
// 1080.253 us; speedup vs baseline: 11.2831x; 11.2831x over previous
//
#include <hip/hip_runtime.h>

#define NUM_USERS 100000
#define NUM_ITEMS 50000
#define EMBED_DIM 64
#define N_NODES   (NUM_USERS + NUM_ITEMS)      // 150000
#define N_EDGES   4800000
#define N_LAYERS  3
#define N_QUERY   16384

#define NODE_FLOATS ((size_t)N_NODES * EMBED_DIM)   // 9,600,000
#define NODE_FLOAT4 (NODE_FLOATS / 4)                // 2,400,000
#define SCAN_BLOCKS ((N_NODES + 255) / 256)          // 586

// ---------------------------------------------------------------------------
// init: acc = h = ego = concat(user_emb, item_emb)
// ---------------------------------------------------------------------------
__global__ void init_kernel(const float4* __restrict__ ue4,
                            const float4* __restrict__ ie4,
                            float4* __restrict__ acc,
                            float4* __restrict__ h) {
    size_t i = (size_t)blockIdx.x * blockDim.x + threadIdx.x;
    if (i >= NODE_FLOAT4) return;
    const size_t user_f4 = (size_t)NUM_USERS * EMBED_DIM / 4;
    float4 v = (i < user_f4) ? ue4[i] : ie4[i - user_f4];
    acc[i] = v;
    h[i]   = v;
}

// ---------------------------------------------------------------------------
// CSR build step 1: histogram of row degrees
// ---------------------------------------------------------------------------
__global__ void hist_kernel(const int* __restrict__ rows, int* __restrict__ cnt) {
    int stride = gridDim.x * blockDim.x;
    for (size_t e = (size_t)blockIdx.x * blockDim.x + threadIdx.x; e < N_EDGES; e += stride)
        atomicAdd(&cnt[rows[e]], 1);
}

// ---------------------------------------------------------------------------
// CSR build step 2a: per-block exclusive scan of cnt -> row_ptr, block sums
// ---------------------------------------------------------------------------
__global__ void scan_block_kernel(const int* __restrict__ cnt,
                                  int* __restrict__ row_ptr,
                                  int* __restrict__ bsums) {
    __shared__ int tmp[256];
    int i = blockIdx.x * 256 + threadIdx.x;
    int v = (i < N_NODES) ? cnt[i] : 0;
    tmp[threadIdx.x] = v;
    __syncthreads();
    #pragma unroll
    for (int off = 1; off < 256; off <<= 1) {
        int t = (threadIdx.x >= off) ? tmp[threadIdx.x - off] : 0;
        __syncthreads();
        tmp[threadIdx.x] += t;
        __syncthreads();
    }
    if (i < N_NODES) row_ptr[i] = tmp[threadIdx.x] - v;  // exclusive
    if (threadIdx.x == 255) bsums[blockIdx.x] = tmp[255];
}

// ---------------------------------------------------------------------------
// CSR build step 2b: single-block exclusive scan of block sums (586 <= 1024)
// ---------------------------------------------------------------------------
__global__ void scan_sums_kernel(int* __restrict__ bsums, int nb) {
    __shared__ int tmp[1024];
    int v = (threadIdx.x < nb) ? bsums[threadIdx.x] : 0;
    tmp[threadIdx.x] = v;
    __syncthreads();
    #pragma unroll
    for (int off = 1; off < 1024; off <<= 1) {
        int t = (threadIdx.x >= off) ? tmp[threadIdx.x - off] : 0;
        __syncthreads();
        tmp[threadIdx.x] += t;
        __syncthreads();
    }
    if (threadIdx.x < nb) bsums[threadIdx.x] = tmp[threadIdx.x] - v;  // exclusive
}

// ---------------------------------------------------------------------------
// CSR build step 2c: add block offsets; set terminator
// ---------------------------------------------------------------------------
__global__ void scan_add_kernel(int* __restrict__ row_ptr,
                                const int* __restrict__ bsums) {
    int i = blockIdx.x * 256 + threadIdx.x;
    if (i < N_NODES) row_ptr[i] += bsums[blockIdx.x];
    if (blockIdx.x == 0 && threadIdx.x == 0) row_ptr[N_NODES] = N_EDGES;
}

// ---------------------------------------------------------------------------
// CSR build step 3: scatter edges into CSR slots
// ---------------------------------------------------------------------------
__global__ void scatter_kernel(const int* __restrict__ rows,
                               const int* __restrict__ cols,
                               const float* __restrict__ vals,
                               const int* __restrict__ row_ptr,
                               int* __restrict__ cnt,
                               int* __restrict__ ccol,
                               float* __restrict__ cval) {
    int stride = gridDim.x * blockDim.x;
    for (size_t e = (size_t)blockIdx.x * blockDim.x + threadIdx.x; e < N_EDGES; e += stride) {
        int r = rows[e];
        int pos = row_ptr[r] + atomicAdd(&cnt[r], 1);
        ccol[pos] = cols[e];
        cval[pos] = vals[e];
    }
}

// ---------------------------------------------------------------------------
// gather-SpMM: one 64-lane wave per row, lane d owns dim d.
// hn[r] = sum_e val_e * h[col_e];  acc[r] += hn[r]  (fused)
// ---------------------------------------------------------------------------
template<bool WRITE_HN>
__global__ void spmm_csr_kernel(const int* __restrict__ row_ptr,
                                const int* __restrict__ ccol,
                                const float* __restrict__ cval,
                                const float* __restrict__ h,
                                float* __restrict__ hn,
                                float* __restrict__ acc) {
    int wave = (int)(((size_t)blockIdx.x * blockDim.x + threadIdx.x) >> 6);
    int lane = threadIdx.x & 63;
    if (wave >= N_NODES) return;

    int s = row_ptr[wave];
    int e = row_ptr[wave + 1];

    float a = 0.0f;
    int i = s;
    // unroll-4: 4 independent gathers in flight
    for (; i + 4 <= e; i += 4) {
        int   c0 = ccol[i],   c1 = ccol[i+1], c2 = ccol[i+2], c3 = ccol[i+3];
        float v0 = cval[i],   v1 = cval[i+1], v2 = cval[i+2], v3 = cval[i+3];
        float x0 = h[(size_t)c0 * EMBED_DIM + lane];
        float x1 = h[(size_t)c1 * EMBED_DIM + lane];
        float x2 = h[(size_t)c2 * EMBED_DIM + lane];
        float x3 = h[(size_t)c3 * EMBED_DIM + lane];
        a = fmaf(v0, x0, a);
        a = fmaf(v1, x1, a);
        a = fmaf(v2, x2, a);
        a = fmaf(v3, x3, a);
    }
    for (; i < e; ++i)
        a = fmaf(cval[i], h[(size_t)ccol[i] * EMBED_DIM + lane], a);

    size_t o = (size_t)wave * EMBED_DIM + lane;
    if (WRITE_HN) hn[o] = a;
    acc[o] += a;
}

// ---------------------------------------------------------------------------
// out[q] = dot(acc[users[q]], acc[NUM_USERS + items[q]]) / 16
// ---------------------------------------------------------------------------
__global__ void dot_kernel(const int* __restrict__ users,
                           const int* __restrict__ items,
                           const float* __restrict__ acc,
                           float* __restrict__ out) {
    int lane = threadIdx.x & 63;
    int wave = threadIdx.x >> 6;
    int q    = blockIdx.x * (blockDim.x >> 6) + wave;
    if (q >= N_QUERY) return;

    int u  = users[q];
    int it = items[q];

    float a = acc[(size_t)u * EMBED_DIM + lane];
    float b = acc[((size_t)NUM_USERS + it) * EMBED_DIM + lane];
    float p = a * b;

    #pragma unroll
    for (int off = 32; off >= 1; off >>= 1)
        p += __shfl_xor(p, off, 64);

    if (lane == 0)
        out[q] = p * (1.0f / 16.0f);   // (acc/4)·(acc/4)
}

// ---------------------------------------------------------------------------
extern "C" void kernel_launch(void* const* d_in, const int* in_sizes, int n_in,
                              void* d_out, int out_size, void* d_ws, size_t ws_size,
                              hipStream_t stream) {
    const int*   users = (const int*)  d_in[0];
    const int*   items = (const int*)  d_in[1];
    const float* ue    = (const float*)d_in[2];
    const float* ie    = (const float*)d_in[3];
    const int*   rows  = (const int*)  d_in[4];
    const int*   cols  = (const int*)  d_in[5];
    const float* vals  = (const float*)d_in[6];
    float*       out   = (float*)d_out;

    // workspace layout (~155.4 MB)
    float* acc     = (float*)d_ws;                 // 9.6M f
    float* h       = acc + NODE_FLOATS;            // 9.6M f
    float* hn      = h + NODE_FLOATS;              // 9.6M f
    float* cval    = hn + NODE_FLOATS;             // 4.8M f
    int*   ccol    = (int*)(cval + N_EDGES);       // 4.8M i
    int*   row_ptr = ccol + N_EDGES;               // 150,016 i (incl. pad)
    int*   cnt     = row_ptr + 150016;             // 150,000 i
    int*   bsums   = cnt + N_NODES;                // 1,024 i

    int vec_blocks = (int)((NODE_FLOAT4 + 255) / 256);

    // ---- CSR build ----
    hipMemsetAsync(cnt, 0, (size_t)N_NODES * sizeof(int), stream);
    init_kernel<<<vec_blocks, 256, 0, stream>>>(
        (const float4*)ue, (const float4*)ie, (float4*)acc, (float4*)h);
    hist_kernel<<<4096, 256, 0, stream>>>(rows, cnt);
    scan_block_kernel<<<SCAN_BLOCKS, 256, 0, stream>>>(cnt, row_ptr, bsums);
    scan_sums_kernel<<<1, 1024, 0, stream>>>(bsums, SCAN_BLOCKS);
    scan_add_kernel<<<SCAN_BLOCKS, 256, 0, stream>>>(row_ptr, bsums);
    hipMemsetAsync(cnt, 0, (size_t)N_NODES * sizeof(int), stream);
    scatter_kernel<<<4096, 256, 0, stream>>>(rows, cols, vals, row_ptr, cnt, ccol, cval);

    // ---- 3 gather-SpMM layers (acc-add fused) ----
    int spmm_blocks = (N_NODES * 64 + 255) / 256;   // one wave per row
    float* cur  = h;
    float* next = hn;
    for (int layer = 0; layer < N_LAYERS; ++layer) {
        if (layer < N_LAYERS - 1)
            spmm_csr_kernel<true><<<spmm_blocks, 256, 0, stream>>>(
                row_ptr, ccol, cval, cur, next, acc);
        else
            spmm_csr_kernel<false><<<spmm_blocks, 256, 0, stream>>>(
                row_ptr, ccol, cval, cur, next, acc);
        float* t = cur; cur = next; next = t;
    }

    // ---- epilogue dot products ----
    dot_kernel<<<(N_QUERY + 3) / 4, 256, 0, stream>>>(users, items, acc, out);
}

// Round 3
// 893.027 us; speedup vs baseline: 13.6487x; 1.2097x over previous
//
#include <hip/hip_runtime.h>

#define NUM_USERS 100000
#define NUM_ITEMS 50000
#define EMBED_DIM 64
#define N_NODES   (NUM_USERS + NUM_ITEMS)      // 150000
#define N_EDGES   4800000
#define N_LAYERS  3
#define N_QUERY   16384

#define NODE_FLOATS ((size_t)N_NODES * EMBED_DIM)   // 9,600,000
#define NODE_FLOAT4 (NODE_FLOATS / 4)                // 2,400,000
#define SCAN_BLOCKS ((N_NODES + 255) / 256)          // 586

// ---------------------------------------------------------------------------
// init: acc = h = ego = concat(user_emb, item_emb)
// ---------------------------------------------------------------------------
__global__ void init_kernel(const float4* __restrict__ ue4,
                            const float4* __restrict__ ie4,
                            float4* __restrict__ acc,
                            float4* __restrict__ h) {
    size_t i = (size_t)blockIdx.x * blockDim.x + threadIdx.x;
    if (i >= NODE_FLOAT4) return;
    const size_t user_f4 = (size_t)NUM_USERS * EMBED_DIM / 4;
    float4 v = (i < user_f4) ? ue4[i] : ie4[i - user_f4];
    acc[i] = v;
    h[i]   = v;
}

// ---------------------------------------------------------------------------
// CSR build step 1: histogram of row degrees + per-edge local slot
// ---------------------------------------------------------------------------
__global__ void hist_kernel(const int* __restrict__ rows,
                            int* __restrict__ cnt,
                            int* __restrict__ loc) {
    int stride = gridDim.x * blockDim.x;
    for (size_t e = (size_t)blockIdx.x * blockDim.x + threadIdx.x; e < N_EDGES; e += stride)
        loc[e] = atomicAdd(&cnt[rows[e]], 1);
}

// ---------------------------------------------------------------------------
// CSR build step 2a: per-block exclusive scan of cnt -> row_ptr, block sums
// ---------------------------------------------------------------------------
__global__ void scan_block_kernel(const int* __restrict__ cnt,
                                  int* __restrict__ row_ptr,
                                  int* __restrict__ bsums) {
    __shared__ int tmp[256];
    int i = blockIdx.x * 256 + threadIdx.x;
    int v = (i < N_NODES) ? cnt[i] : 0;
    tmp[threadIdx.x] = v;
    __syncthreads();
    #pragma unroll
    for (int off = 1; off < 256; off <<= 1) {
        int t = (threadIdx.x >= off) ? tmp[threadIdx.x - off] : 0;
        __syncthreads();
        tmp[threadIdx.x] += t;
        __syncthreads();
    }
    if (i < N_NODES) row_ptr[i] = tmp[threadIdx.x] - v;  // exclusive
    if (threadIdx.x == 255) bsums[blockIdx.x] = tmp[255];
}

// ---------------------------------------------------------------------------
// CSR build step 2b: single-block exclusive scan of block sums (586 <= 1024)
// ---------------------------------------------------------------------------
__global__ void scan_sums_kernel(int* __restrict__ bsums, int nb) {
    __shared__ int tmp[1024];
    int v = (threadIdx.x < nb) ? bsums[threadIdx.x] : 0;
    tmp[threadIdx.x] = v;
    __syncthreads();
    #pragma unroll
    for (int off = 1; off < 1024; off <<= 1) {
        int t = (threadIdx.x >= off) ? tmp[threadIdx.x - off] : 0;
        __syncthreads();
        tmp[threadIdx.x] += t;
        __syncthreads();
    }
    if (threadIdx.x < nb) bsums[threadIdx.x] = tmp[threadIdx.x] - v;  // exclusive
}

// ---------------------------------------------------------------------------
// CSR build step 2c: add block offsets; set terminator
// ---------------------------------------------------------------------------
__global__ void scan_add_kernel(int* __restrict__ row_ptr,
                                const int* __restrict__ bsums) {
    int i = blockIdx.x * 256 + threadIdx.x;
    if (i < N_NODES) row_ptr[i] += bsums[blockIdx.x];
    if (blockIdx.x == 0 && threadIdx.x == 0) row_ptr[N_NODES] = N_EDGES;
}

// ---------------------------------------------------------------------------
// CSR build step 3: scatter edges into CSR slots — no atomics, one int2 write
// ---------------------------------------------------------------------------
__global__ void scatter_kernel(const int* __restrict__ rows,
                               const int* __restrict__ cols,
                               const float* __restrict__ vals,
                               const int* __restrict__ loc,
                               const int* __restrict__ row_ptr,
                               int2* __restrict__ pair) {
    int stride = gridDim.x * blockDim.x;
    for (size_t e = (size_t)blockIdx.x * blockDim.x + threadIdx.x; e < N_EDGES; e += stride) {
        int r   = rows[e];
        int pos = row_ptr[r] + loc[e];
        int2 p;
        p.x = cols[e];
        p.y = __float_as_int(vals[e]);
        pair[pos] = p;
    }
}

// ---------------------------------------------------------------------------
// gather-SpMM: one 64-lane wave per row, lane d owns dim d.
// hn[r] = sum_e val_e * h[col_e];  acc[r] += hn[r]  (fused)
// ---------------------------------------------------------------------------
template<bool WRITE_HN>
__global__ void spmm_csr_kernel(const int* __restrict__ row_ptr,
                                const int2* __restrict__ pair,
                                const float* __restrict__ h,
                                float* __restrict__ hn,
                                float* __restrict__ acc) {
    int wave = (int)(((size_t)blockIdx.x * blockDim.x + threadIdx.x) >> 6);
    int lane = threadIdx.x & 63;
    if (wave >= N_NODES) return;

    int s = row_ptr[wave];
    int e = row_ptr[wave + 1];

    float a = 0.0f;
    int i = s;
    // unroll-8: 8 independent gathers in flight
    for (; i + 8 <= e; i += 8) {
        int2 p0 = pair[i],   p1 = pair[i+1], p2 = pair[i+2], p3 = pair[i+3];
        int2 p4 = pair[i+4], p5 = pair[i+5], p6 = pair[i+6], p7 = pair[i+7];
        float x0 = h[(size_t)p0.x * EMBED_DIM + lane];
        float x1 = h[(size_t)p1.x * EMBED_DIM + lane];
        float x2 = h[(size_t)p2.x * EMBED_DIM + lane];
        float x3 = h[(size_t)p3.x * EMBED_DIM + lane];
        float x4 = h[(size_t)p4.x * EMBED_DIM + lane];
        float x5 = h[(size_t)p5.x * EMBED_DIM + lane];
        float x6 = h[(size_t)p6.x * EMBED_DIM + lane];
        float x7 = h[(size_t)p7.x * EMBED_DIM + lane];
        a = fmaf(__int_as_float(p0.y), x0, a);
        a = fmaf(__int_as_float(p1.y), x1, a);
        a = fmaf(__int_as_float(p2.y), x2, a);
        a = fmaf(__int_as_float(p3.y), x3, a);
        a = fmaf(__int_as_float(p4.y), x4, a);
        a = fmaf(__int_as_float(p5.y), x5, a);
        a = fmaf(__int_as_float(p6.y), x6, a);
        a = fmaf(__int_as_float(p7.y), x7, a);
    }
    for (; i < e; ++i) {
        int2 p = pair[i];
        a = fmaf(__int_as_float(p.y), h[(size_t)p.x * EMBED_DIM + lane], a);
    }

    size_t o = (size_t)wave * EMBED_DIM + lane;
    if (WRITE_HN) hn[o] = a;
    acc[o] += a;
}

// ---------------------------------------------------------------------------
// out[q] = dot(acc[users[q]], acc[NUM_USERS + items[q]]) / 16
// ---------------------------------------------------------------------------
__global__ void dot_kernel(const int* __restrict__ users,
                           const int* __restrict__ items,
                           const float* __restrict__ acc,
                           float* __restrict__ out) {
    int lane = threadIdx.x & 63;
    int wave = threadIdx.x >> 6;
    int q    = blockIdx.x * (blockDim.x >> 6) + wave;
    if (q >= N_QUERY) return;

    int u  = users[q];
    int it = items[q];

    float a = acc[(size_t)u * EMBED_DIM + lane];
    float b = acc[((size_t)NUM_USERS + it) * EMBED_DIM + lane];
    float p = a * b;

    #pragma unroll
    for (int off = 32; off >= 1; off >>= 1)
        p += __shfl_xor(p, off, 64);

    if (lane == 0)
        out[q] = p * (1.0f / 16.0f);   // (acc/4)·(acc/4)
}

// ---------------------------------------------------------------------------
extern "C" void kernel_launch(void* const* d_in, const int* in_sizes, int n_in,
                              void* d_out, int out_size, void* d_ws, size_t ws_size,
                              hipStream_t stream) {
    const int*   users = (const int*)  d_in[0];
    const int*   items = (const int*)  d_in[1];
    const float* ue    = (const float*)d_in[2];
    const float* ie    = (const float*)d_in[3];
    const int*   rows  = (const int*)  d_in[4];
    const int*   cols  = (const int*)  d_in[5];
    const float* vals  = (const float*)d_in[6];
    float*       out   = (float*)d_out;

    // workspace layout (~155 MB)
    float* acc     = (float*)d_ws;                 // 9.6M f
    float* h       = acc + NODE_FLOATS;            // 9.6M f
    float* hn      = h + NODE_FLOATS;              // 9.6M f
    int2*  pair    = (int2*)(hn + NODE_FLOATS);    // 4.8M int2
    int*   row_ptr = (int*)(pair + N_EDGES);       // 150,016 i
    int*   cnt     = row_ptr + 150016;             // 150,000 i
    int*   bsums   = cnt + N_NODES;                // 1,024 i
    int*   loc     = (int*)hn;                     // aliases hn (dead until layer 1)

    int vec_blocks = (int)((NODE_FLOAT4 + 255) / 256);

    // ---- CSR build ----
    hipMemsetAsync(cnt, 0, (size_t)N_NODES * sizeof(int), stream);
    init_kernel<<<vec_blocks, 256, 0, stream>>>(
        (const float4*)ue, (const float4*)ie, (float4*)acc, (float4*)h);
    hist_kernel<<<4096, 256, 0, stream>>>(rows, cnt, loc);
    scan_block_kernel<<<SCAN_BLOCKS, 256, 0, stream>>>(cnt, row_ptr, bsums);
    scan_sums_kernel<<<1, 1024, 0, stream>>>(bsums, SCAN_BLOCKS);
    scan_add_kernel<<<SCAN_BLOCKS, 256, 0, stream>>>(row_ptr, bsums);
    scatter_kernel<<<4096, 256, 0, stream>>>(rows, cols, vals, loc, row_ptr, pair);

    // ---- 3 gather-SpMM layers (acc-add fused) ----
    int spmm_blocks = (N_NODES * 64 + 255) / 256;   // one wave per row
    float* cur  = h;
    float* next = hn;
    for (int layer = 0; layer < N_LAYERS; ++layer) {
        if (layer < N_LAYERS - 1)
            spmm_csr_kernel<true><<<spmm_blocks, 256, 0, stream>>>(
                row_ptr, pair, cur, next, acc);
        else
            spmm_csr_kernel<false><<<spmm_blocks, 256, 0, stream>>>(
                row_ptr, pair, cur, next, acc);
        float* t = cur; cur = next; next = t;
    }

    // ---- epilogue dot products ----
    dot_kernel<<<(N_QUERY + 3) / 4, 256, 0, stream>>>(users, items, acc, out);
}

// Round 4
// 891.032 us; speedup vs baseline: 13.6792x; 1.0022x over previous
//
#include <hip/hip_runtime.h>

#define NUM_USERS 100000
#define NUM_ITEMS 50000
#define EMBED_DIM 64
#define N_NODES   (NUM_USERS + NUM_ITEMS)      // 150000
#define N_EDGES   4800000
#define N_LAYERS  3
#define N_QUERY   16384

#define NODE_FLOATS ((size_t)N_NODES * EMBED_DIM)   // 9,600,000
#define NODE_FLOAT4 (NODE_FLOATS / 4)                // 2,400,000
#define SCAN_BLOCKS ((N_NODES + 255) / 256)          // 586

#define NPART 8
#define ROWS_PER_PART (N_NODES / NPART)              // 18750 (exact)

// ---------------------------------------------------------------------------
// init: acc = ego = concat(user_emb, item_emb)   (no h copy — layer 1 reads
// the embeddings directly via pointer-select)
// ---------------------------------------------------------------------------
__global__ void init_acc_kernel(const float4* __restrict__ ue4,
                                const float4* __restrict__ ie4,
                                float4* __restrict__ acc) {
    size_t i = (size_t)blockIdx.x * blockDim.x + threadIdx.x;
    if (i >= NODE_FLOAT4) return;
    const size_t user_f4 = (size_t)NUM_USERS * EMBED_DIM / 4;
    acc[i] = (i < user_f4) ? ue4[i] : ie4[i - user_f4];
}

// ---------------------------------------------------------------------------
// flag queried nodes; compact to qlist
// ---------------------------------------------------------------------------
__global__ void flag_kernel(const int* __restrict__ users,
                            const int* __restrict__ items,
                            int* __restrict__ flag) {
    int i = blockIdx.x * blockDim.x + threadIdx.x;
    if (i < N_QUERY) {
        flag[users[i]] = 1;
        flag[NUM_USERS + items[i]] = 1;
    }
}

__global__ void compact_kernel(const int* __restrict__ flag,
                               int* __restrict__ qlist,
                               int* __restrict__ qn) {
    int i = blockIdx.x * blockDim.x + threadIdx.x;
    if (i < N_NODES && flag[i])
        qlist[atomicAdd(qn, 1)] = i;
}

// ---------------------------------------------------------------------------
// CSR build step 1: row-partitioned histogram. Blocks with bid&7==g own rows
// [g*RPP, (g+1)*RPP) — atomics stay XCD-local, no cross-XCD line ping-pong.
// ---------------------------------------------------------------------------
__global__ void hist_part_kernel(const int* __restrict__ rows,
                                 int* __restrict__ cnt) {
    int part = blockIdx.x & (NPART - 1);
    int lo = part * ROWS_PER_PART;
    int hi = lo + ROWS_PER_PART;
    size_t gb     = blockIdx.x >> 3;
    size_t stride = (size_t)(gridDim.x >> 3) * blockDim.x;
    for (size_t e = gb * blockDim.x + threadIdx.x; e < N_EDGES; e += stride) {
        int r = rows[e];
        if (r >= lo && r < hi)
            atomicAdd(&cnt[r], 1);
    }
}

// ---------------------------------------------------------------------------
// CSR build step 2a/2b/2c: exclusive scan of cnt -> row_ptr
// ---------------------------------------------------------------------------
__global__ void scan_block_kernel(const int* __restrict__ cnt,
                                  int* __restrict__ row_ptr,
                                  int* __restrict__ bsums) {
    __shared__ int tmp[256];
    int i = blockIdx.x * 256 + threadIdx.x;
    int v = (i < N_NODES) ? cnt[i] : 0;
    tmp[threadIdx.x] = v;
    __syncthreads();
    #pragma unroll
    for (int off = 1; off < 256; off <<= 1) {
        int t = (threadIdx.x >= off) ? tmp[threadIdx.x - off] : 0;
        __syncthreads();
        tmp[threadIdx.x] += t;
        __syncthreads();
    }
    if (i < N_NODES) row_ptr[i] = tmp[threadIdx.x] - v;  // exclusive
    if (threadIdx.x == 255) bsums[blockIdx.x] = tmp[255];
}

__global__ void scan_sums_kernel(int* __restrict__ bsums, int nb) {
    __shared__ int tmp[1024];
    int v = (threadIdx.x < nb) ? bsums[threadIdx.x] : 0;
    tmp[threadIdx.x] = v;
    __syncthreads();
    #pragma unroll
    for (int off = 1; off < 1024; off <<= 1) {
        int t = (threadIdx.x >= off) ? tmp[threadIdx.x - off] : 0;
        __syncthreads();
        tmp[threadIdx.x] += t;
        __syncthreads();
    }
    if (threadIdx.x < nb) bsums[threadIdx.x] = tmp[threadIdx.x] - v;  // exclusive
}

__global__ void scan_add_kernel(int* __restrict__ row_ptr,
                                const int* __restrict__ bsums) {
    int i = blockIdx.x * 256 + threadIdx.x;
    if (i < N_NODES) row_ptr[i] += bsums[blockIdx.x];
    if (blockIdx.x == 0 && threadIdx.x == 0) row_ptr[N_NODES] = N_EDGES;
}

// ---------------------------------------------------------------------------
// CSR build step 3: row-partitioned scatter. pos ranges are row-partitioned
// so pair[] lines are written by a single XCD; atomics XCD-local.
// ---------------------------------------------------------------------------
__global__ void scatter_part_kernel(const int* __restrict__ rows,
                                    const int* __restrict__ cols,
                                    const float* __restrict__ vals,
                                    const int* __restrict__ row_ptr,
                                    int* __restrict__ cnt2,
                                    int2* __restrict__ pair) {
    int part = blockIdx.x & (NPART - 1);
    int lo = part * ROWS_PER_PART;
    int hi = lo + ROWS_PER_PART;
    size_t gb     = blockIdx.x >> 3;
    size_t stride = (size_t)(gridDim.x >> 3) * blockDim.x;
    for (size_t e = gb * blockDim.x + threadIdx.x; e < N_EDGES; e += stride) {
        int r = rows[e];
        if (r >= lo && r < hi) {
            int pos = row_ptr[r] + atomicAdd(&cnt2[r], 1);
            int2 p;
            p.x = cols[e];
            p.y = __float_as_int(vals[e]);
            pair[pos] = p;
        }
    }
}

// ---------------------------------------------------------------------------
// gather-SpMM body: one 64-lane wave per row, lane d owns dim d.
// GATHER(c) must return h[c][lane].
// ---------------------------------------------------------------------------
#define SPMM_BODY(GATHER)                                                     \
    float a = 0.0f;                                                           \
    int i = s;                                                                \
    for (; i + 8 <= e; i += 8) {                                              \
        int2 p0 = pair[i],   p1 = pair[i+1], p2 = pair[i+2], p3 = pair[i+3];  \
        int2 p4 = pair[i+4], p5 = pair[i+5], p6 = pair[i+6], p7 = pair[i+7];  \
        float x0 = GATHER(p0.x); float x1 = GATHER(p1.x);                     \
        float x2 = GATHER(p2.x); float x3 = GATHER(p3.x);                     \
        float x4 = GATHER(p4.x); float x5 = GATHER(p5.x);                     \
        float x6 = GATHER(p6.x); float x7 = GATHER(p7.x);                     \
        a = fmaf(__int_as_float(p0.y), x0, a);                                \
        a = fmaf(__int_as_float(p1.y), x1, a);                                \
        a = fmaf(__int_as_float(p2.y), x2, a);                                \
        a = fmaf(__int_as_float(p3.y), x3, a);                                \
        a = fmaf(__int_as_float(p4.y), x4, a);                                \
        a = fmaf(__int_as_float(p5.y), x5, a);                                \
        a = fmaf(__int_as_float(p6.y), x6, a);                                \
        a = fmaf(__int_as_float(p7.y), x7, a);                                \
    }                                                                         \
    for (; i < e; ++i) {                                                      \
        int2 p = pair[i];                                                     \
        a = fmaf(__int_as_float(p.y), GATHER(p.x), a);                        \
    }

// layer 1: gather from virtual ego = [user_emb ; item_emb]
__global__ void spmm_l1_kernel(const int* __restrict__ row_ptr,
                               const int2* __restrict__ pair,
                               const float* __restrict__ ue,
                               const float* __restrict__ ie,
                               float* __restrict__ hn,
                               float* __restrict__ acc) {
    int wave = (int)(((size_t)blockIdx.x * blockDim.x + threadIdx.x) >> 6);
    int lane = threadIdx.x & 63;
    if (wave >= N_NODES) return;
    int s = row_ptr[wave];
    int e = row_ptr[wave + 1];

    #define GATHER_EGO(c) \
        (((c) < NUM_USERS) ? ue[(size_t)(c) * EMBED_DIM + lane] \
                           : ie[(size_t)((c) - NUM_USERS) * EMBED_DIM + lane])
    SPMM_BODY(GATHER_EGO)
    #undef GATHER_EGO

    size_t o = (size_t)wave * EMBED_DIM + lane;
    hn[o] = a;
    acc[o] += a;
}

// layer 2: gather from h, all rows
__global__ void spmm_l2_kernel(const int* __restrict__ row_ptr,
                               const int2* __restrict__ pair,
                               const float* __restrict__ h,
                               float* __restrict__ hn,
                               float* __restrict__ acc) {
    int wave = (int)(((size_t)blockIdx.x * blockDim.x + threadIdx.x) >> 6);
    int lane = threadIdx.x & 63;
    if (wave >= N_NODES) return;
    int s = row_ptr[wave];
    int e = row_ptr[wave + 1];

    #define GATHER_H(c) (h[(size_t)(c) * EMBED_DIM + lane])
    SPMM_BODY(GATHER_H)
    #undef GATHER_H

    size_t o = (size_t)wave * EMBED_DIM + lane;
    hn[o] = a;
    acc[o] += a;
}

// layer 3: only queried rows (qlist), acc-add only
__global__ void spmm_l3_kernel(const int* __restrict__ row_ptr,
                               const int2* __restrict__ pair,
                               const float* __restrict__ h,
                               float* __restrict__ acc,
                               const int* __restrict__ qlist,
                               const int* __restrict__ qn) {
    int wid  = (int)(((size_t)blockIdx.x * blockDim.x + threadIdx.x) >> 6);
    int lane = threadIdx.x & 63;
    if (wid >= *qn) return;
    int row = qlist[wid];
    int s = row_ptr[row];
    int e = row_ptr[row + 1];

    #define GATHER_H(c) (h[(size_t)(c) * EMBED_DIM + lane])
    SPMM_BODY(GATHER_H)
    #undef GATHER_H

    acc[(size_t)row * EMBED_DIM + lane] += a;
}

// ---------------------------------------------------------------------------
// out[q] = dot(acc[users[q]], acc[NUM_USERS + items[q]]) / 16
// ---------------------------------------------------------------------------
__global__ void dot_kernel(const int* __restrict__ users,
                           const int* __restrict__ items,
                           const float* __restrict__ acc,
                           float* __restrict__ out) {
    int lane = threadIdx.x & 63;
    int wave = threadIdx.x >> 6;
    int q    = blockIdx.x * (blockDim.x >> 6) + wave;
    if (q >= N_QUERY) return;

    float a = acc[(size_t)users[q] * EMBED_DIM + lane];
    float b = acc[((size_t)NUM_USERS + items[q]) * EMBED_DIM + lane];
    float p = a * b;

    #pragma unroll
    for (int off = 32; off >= 1; off >>= 1)
        p += __shfl_xor(p, off, 64);

    if (lane == 0)
        out[q] = p * (1.0f / 16.0f);   // (acc/4)·(acc/4)
}

// ---------------------------------------------------------------------------
extern "C" void kernel_launch(void* const* d_in, const int* in_sizes, int n_in,
                              void* d_out, int out_size, void* d_ws, size_t ws_size,
                              hipStream_t stream) {
    const int*   users = (const int*)  d_in[0];
    const int*   items = (const int*)  d_in[1];
    const float* ue    = (const float*)d_in[2];
    const float* ie    = (const float*)d_in[3];
    const int*   rows  = (const int*)  d_in[4];
    const int*   cols  = (const int*)  d_in[5];
    const float* vals  = (const float*)d_in[6];
    float*       out   = (float*)d_out;

    // workspace layout (~156 MB)
    float* acc     = (float*)d_ws;                 // 9.6M f
    float* hA      = acc + NODE_FLOATS;            // 9.6M f
    float* hB      = hA + NODE_FLOATS;             // 9.6M f
    int2*  pair    = (int2*)(hB + NODE_FLOATS);    // 4.8M int2
    int*   row_ptr = (int*)(pair + N_EDGES);       // 150,016 i
    int*   cnt     = row_ptr + 150016;             // 150,000 i
    int*   cnt2    = cnt + N_NODES;                // 150,000 i
    int*   flag    = cnt2 + N_NODES;               // 150,000 i
    int*   qn      = flag + N_NODES;               // 1 i
    int*   bsums   = qn + 1;                       // 1,024 i (pad to align)
    int*   qlist   = bsums + 1024;                 // 32,768 i

    int vec_blocks = (int)((NODE_FLOAT4 + 255) / 256);

    // zero cnt, cnt2, flag, qn in one shot (contiguous)
    hipMemsetAsync(cnt, 0, (size_t)(3 * N_NODES + 1) * sizeof(int), stream);

    init_acc_kernel<<<vec_blocks, 256, 0, stream>>>(
        (const float4*)ue, (const float4*)ie, (float4*)acc);
    flag_kernel<<<(N_QUERY + 255) / 256, 256, 0, stream>>>(users, items, flag);

    // ---- CSR build (row-partitioned, XCD-local atomics) ----
    hist_part_kernel<<<4096, 256, 0, stream>>>(rows, cnt);
    scan_block_kernel<<<SCAN_BLOCKS, 256, 0, stream>>>(cnt, row_ptr, bsums);
    scan_sums_kernel<<<1, 1024, 0, stream>>>(bsums, SCAN_BLOCKS);
    scan_add_kernel<<<SCAN_BLOCKS, 256, 0, stream>>>(row_ptr, bsums);
    scatter_part_kernel<<<4096, 256, 0, stream>>>(rows, cols, vals, row_ptr, cnt2, pair);

    // ---- SpMM layers ----
    int spmm_blocks = (N_NODES * 64 + 255) / 256;   // one wave per row
    spmm_l1_kernel<<<spmm_blocks, 256, 0, stream>>>(row_ptr, pair, ue, ie, hA, acc);
    spmm_l2_kernel<<<spmm_blocks, 256, 0, stream>>>(row_ptr, pair, hA, hB, acc);

    compact_kernel<<<SCAN_BLOCKS, 256, 0, stream>>>(flag, qlist, qn);

    // layer 3 over at most 2*N_QUERY rows
    int q_blocks = (2 * N_QUERY * 64 + 255) / 256;
    spmm_l3_kernel<<<q_blocks, 256, 0, stream>>>(row_ptr, pair, hB, acc, qlist, qn);

    // ---- epilogue dot products ----
    dot_kernel<<<(N_QUERY + 3) / 4, 256, 0, stream>>>(users, items, acc, out);
}

// Round 5
// 872.285 us; speedup vs baseline: 13.9732x; 1.0215x over previous
//
#include <hip/hip_runtime.h>

#define NUM_USERS 100000
#define NUM_ITEMS 50000
#define EMBED_DIM 64
#define N_NODES   (NUM_USERS + NUM_ITEMS)      // 150000
#define N_EDGES   4800000
#define N_LAYERS  3
#define N_QUERY   16384

#define NODE_FLOATS ((size_t)N_NODES * EMBED_DIM)   // 9,600,000
#define NODE_FLOAT4 (NODE_FLOATS / 4)                // 2,400,000
#define SCAN_BLOCKS ((N_NODES + 255) / 256)          // 586

#define NBUCKET    16
#define BROWS      9376                              // rows per bucket (16*9376=150016)
#define BUCKET_CAP 310016                            // mean 300K + 18 sigma
#define CNT_STRIDE 150016
#define BIN_EDGES  4096
#define BIN_BLOCKS ((N_EDGES + BIN_EDGES - 1) / BIN_EDGES)  // 1172

// ---------------------------------------------------------------------------
// init: acc = ego = concat(user_emb, item_emb); also init bucket cursors
// ---------------------------------------------------------------------------
__global__ void init_acc_kernel(const float4* __restrict__ ue4,
                                const float4* __restrict__ ie4,
                                float4* __restrict__ acc,
                                int* __restrict__ gcur) {
    if (blockIdx.x == 0 && threadIdx.x < NBUCKET)
        gcur[threadIdx.x] = threadIdx.x * BUCKET_CAP;
    size_t i = (size_t)blockIdx.x * blockDim.x + threadIdx.x;
    if (i >= NODE_FLOAT4) return;
    const size_t user_f4 = (size_t)NUM_USERS * EMBED_DIM / 4;
    acc[i] = (i < user_f4) ? ue4[i] : ie4[i - user_f4];
}

// ---------------------------------------------------------------------------
// flag queried nodes; compact to qlist
// ---------------------------------------------------------------------------
__global__ void flag_kernel(const int* __restrict__ users,
                            const int* __restrict__ items,
                            int* __restrict__ flag) {
    int i = blockIdx.x * blockDim.x + threadIdx.x;
    if (i < N_QUERY) {
        flag[users[i]] = 1;
        flag[NUM_USERS + items[i]] = 1;
    }
}

__global__ void compact_kernel(const int* __restrict__ flag,
                               int* __restrict__ qlist,
                               int* __restrict__ qn) {
    int i = blockIdx.x * blockDim.x + threadIdx.x;
    if (i < N_NODES && flag[i])
        qlist[atomicAdd(qn, 1)] = i;
}

// ---------------------------------------------------------------------------
// bin: single read of edges -> 16 row-range buckets, LDS-staged, coalesced
// record write-out. Fuses per-row histogram into per-XCD replica counters.
// ---------------------------------------------------------------------------
__global__ void __launch_bounds__(256) bin_kernel(
        const int* __restrict__ rows,
        const int* __restrict__ cols,
        const float* __restrict__ vals,
        int* __restrict__ cnt8,      // [8][CNT_STRIDE] replicas
        int* __restrict__ gcur,      // [NBUCKET] global cursors
        int* __restrict__ recR,
        int* __restrict__ recC,
        float* __restrict__ recV) {
    __shared__ int   lcnt[NBUCKET];
    __shared__ int   lbase[NBUCKET];
    __shared__ int   loff[NBUCKET];
    __shared__ int   lcur[NBUCKET];
    __shared__ int   sR[BIN_EDGES];
    __shared__ int   sC[BIN_EDGES];
    __shared__ float sV[BIN_EDGES];

    if (threadIdx.x < NBUCKET) lcnt[threadIdx.x] = 0;
    __syncthreads();

    const size_t e0 = (size_t)blockIdx.x * BIN_EDGES;
    int* cntrep = cnt8 + (size_t)(blockIdx.x & 7) * CNT_STRIDE;

    // pass 1: bucket counts + per-row hist (XCD-local replica)
    for (int k = threadIdx.x; k < BIN_EDGES; k += 256) {
        size_t e = e0 + k;
        if (e < N_EDGES) {
            int r = rows[e];
            atomicAdd(&lcnt[r / BROWS], 1);
            atomicAdd(&cntrep[r], 1);
        }
    }
    __syncthreads();

    // claim global ranges; LDS prefix
    if (threadIdx.x < NBUCKET)
        lbase[threadIdx.x] = atomicAdd(&gcur[threadIdx.x], lcnt[threadIdx.x]);
    __syncthreads();
    if (threadIdx.x == 0) {
        int s = 0;
        for (int b = 0; b < NBUCKET; ++b) { loff[b] = s; lcur[b] = s; s += lcnt[b]; }
    }
    __syncthreads();

    // pass 2: stage records bucket-sorted in LDS (rows/cols L2-hot)
    for (int k = threadIdx.x; k < BIN_EDGES; k += 256) {
        size_t e = e0 + k;
        if (e < N_EDGES) {
            int   r = rows[e];
            int   c = cols[e];
            float v = vals[e];
            int slot = atomicAdd(&lcur[r / BROWS], 1);
            sR[slot] = r;
            sC[slot] = c;
            sV[slot] = v;
        }
    }
    __syncthreads();

    // coalesced copy-out per bucket
    for (int b = 0; b < NBUCKET; ++b) {
        int n = lcnt[b], src = loff[b], dst = lbase[b];
        for (int k = threadIdx.x; k < n; k += 256) {
            recR[dst + k] = sR[src + k];
            recC[dst + k] = sC[src + k];
            recV[dst + k] = sV[src + k];
        }
    }
}

// ---------------------------------------------------------------------------
// exclusive scan of summed replica counts -> row_ptr
// ---------------------------------------------------------------------------
__global__ void scan_block_kernel(const int* __restrict__ cnt8,
                                  int* __restrict__ row_ptr,
                                  int* __restrict__ bsums) {
    __shared__ int tmp[256];
    int i = blockIdx.x * 256 + threadIdx.x;
    int v = 0;
    if (i < N_NODES) {
        #pragma unroll
        for (int g = 0; g < 8; ++g)
            v += cnt8[(size_t)g * CNT_STRIDE + i];
    }
    tmp[threadIdx.x] = v;
    __syncthreads();
    #pragma unroll
    for (int off = 1; off < 256; off <<= 1) {
        int t = (threadIdx.x >= off) ? tmp[threadIdx.x - off] : 0;
        __syncthreads();
        tmp[threadIdx.x] += t;
        __syncthreads();
    }
    if (i < N_NODES) row_ptr[i] = tmp[threadIdx.x] - v;  // exclusive
    if (threadIdx.x == 255) bsums[blockIdx.x] = tmp[255];
}

__global__ void scan_sums_kernel(int* __restrict__ bsums, int nb) {
    __shared__ int tmp[1024];
    int v = (threadIdx.x < nb) ? bsums[threadIdx.x] : 0;
    tmp[threadIdx.x] = v;
    __syncthreads();
    #pragma unroll
    for (int off = 1; off < 1024; off <<= 1) {
        int t = (threadIdx.x >= off) ? tmp[threadIdx.x - off] : 0;
        __syncthreads();
        tmp[threadIdx.x] += t;
        __syncthreads();
    }
    if (threadIdx.x < nb) bsums[threadIdx.x] = tmp[threadIdx.x] - v;  // exclusive
}

__global__ void scan_add_kernel(int* __restrict__ row_ptr,
                                const int* __restrict__ bsums) {
    int i = blockIdx.x * 256 + threadIdx.x;
    if (i < N_NODES) row_ptr[i] += bsums[blockIdx.x];
    if (blockIdx.x == 0 && threadIdx.x == 0) row_ptr[N_NODES] = N_EDGES;
}

// ---------------------------------------------------------------------------
// scatter2: bucket = bid&15 (XCD-pinned). Sequential record read, pair write
// confined to the bucket's ~2.4 MB region -> L2-resident, amplification ~1.
// ---------------------------------------------------------------------------
__global__ void scatter2_kernel(const int* __restrict__ recR,
                                const int* __restrict__ recC,
                                const float* __restrict__ recV,
                                const int* __restrict__ gcur,
                                const int* __restrict__ row_ptr,
                                int* __restrict__ cnt2,
                                int2* __restrict__ pair) {
    int b    = blockIdx.x & (NBUCKET - 1);
    int lb   = blockIdx.x >> 4;
    int base = b * BUCKET_CAP;
    int len  = gcur[b] - base;
    int stride = (gridDim.x >> 4) * blockDim.x;
    for (int i = lb * blockDim.x + threadIdx.x; i < len; i += stride) {
        int r   = recR[base + i];
        int pos = row_ptr[r] + atomicAdd(&cnt2[r], 1);
        int2 p;
        p.x = recC[base + i];
        p.y = __float_as_int(recV[base + i]);
        pair[pos] = p;
    }
}

// ---------------------------------------------------------------------------
// gather-SpMM body: one 64-lane wave per row, lane d owns dim d.
// ---------------------------------------------------------------------------
#define SPMM_BODY(GATHER)                                                     \
    float a = 0.0f;                                                           \
    int i = s;                                                                \
    for (; i + 8 <= e; i += 8) {                                              \
        int2 p0 = pair[i],   p1 = pair[i+1], p2 = pair[i+2], p3 = pair[i+3];  \
        int2 p4 = pair[i+4], p5 = pair[i+5], p6 = pair[i+6], p7 = pair[i+7];  \
        float x0 = GATHER(p0.x); float x1 = GATHER(p1.x);                     \
        float x2 = GATHER(p2.x); float x3 = GATHER(p3.x);                     \
        float x4 = GATHER(p4.x); float x5 = GATHER(p5.x);                     \
        float x6 = GATHER(p6.x); float x7 = GATHER(p7.x);                     \
        a = fmaf(__int_as_float(p0.y), x0, a);                                \
        a = fmaf(__int_as_float(p1.y), x1, a);                                \
        a = fmaf(__int_as_float(p2.y), x2, a);                                \
        a = fmaf(__int_as_float(p3.y), x3, a);                                \
        a = fmaf(__int_as_float(p4.y), x4, a);                                \
        a = fmaf(__int_as_float(p5.y), x5, a);                                \
        a = fmaf(__int_as_float(p6.y), x6, a);                                \
        a = fmaf(__int_as_float(p7.y), x7, a);                                \
    }                                                                         \
    for (; i < e; ++i) {                                                      \
        int2 p = pair[i];                                                     \
        a = fmaf(__int_as_float(p.y), GATHER(p.x), a);                        \
    }

// layer 1: gather from virtual ego = [user_emb ; item_emb]
__global__ void spmm_l1_kernel(const int* __restrict__ row_ptr,
                               const int2* __restrict__ pair,
                               const float* __restrict__ ue,
                               const float* __restrict__ ie,
                               float* __restrict__ hn,
                               float* __restrict__ acc) {
    int wave = (int)(((size_t)blockIdx.x * blockDim.x + threadIdx.x) >> 6);
    int lane = threadIdx.x & 63;
    if (wave >= N_NODES) return;
    int s = row_ptr[wave];
    int e = row_ptr[wave + 1];

    #define GATHER_EGO(c) \
        (((c) < NUM_USERS) ? ue[(size_t)(c) * EMBED_DIM + lane] \
                           : ie[(size_t)((c) - NUM_USERS) * EMBED_DIM + lane])
    SPMM_BODY(GATHER_EGO)
    #undef GATHER_EGO

    size_t o = (size_t)wave * EMBED_DIM + lane;
    hn[o] = a;
    acc[o] += a;
}

// layer 2: gather from h, all rows
__global__ void spmm_l2_kernel(const int* __restrict__ row_ptr,
                               const int2* __restrict__ pair,
                               const float* __restrict__ h,
                               float* __restrict__ hn,
                               float* __restrict__ acc) {
    int wave = (int)(((size_t)blockIdx.x * blockDim.x + threadIdx.x) >> 6);
    int lane = threadIdx.x & 63;
    if (wave >= N_NODES) return;
    int s = row_ptr[wave];
    int e = row_ptr[wave + 1];

    #define GATHER_H(c) (h[(size_t)(c) * EMBED_DIM + lane])
    SPMM_BODY(GATHER_H)
    #undef GATHER_H

    size_t o = (size_t)wave * EMBED_DIM + lane;
    hn[o] = a;
    acc[o] += a;
}

// layer 3: only queried rows (qlist), acc-add only
__global__ void spmm_l3_kernel(const int* __restrict__ row_ptr,
                               const int2* __restrict__ pair,
                               const float* __restrict__ h,
                               float* __restrict__ acc,
                               const int* __restrict__ qlist,
                               const int* __restrict__ qn) {
    int wid  = (int)(((size_t)blockIdx.x * blockDim.x + threadIdx.x) >> 6);
    int lane = threadIdx.x & 63;
    if (wid >= *qn) return;
    int row = qlist[wid];
    int s = row_ptr[row];
    int e = row_ptr[row + 1];

    #define GATHER_H(c) (h[(size_t)(c) * EMBED_DIM + lane])
    SPMM_BODY(GATHER_H)
    #undef GATHER_H

    acc[(size_t)row * EMBED_DIM + lane] += a;
}

// ---------------------------------------------------------------------------
// out[q] = dot(acc[users[q]], acc[NUM_USERS + items[q]]) / 16
// ---------------------------------------------------------------------------
__global__ void dot_kernel(const int* __restrict__ users,
                           const int* __restrict__ items,
                           const float* __restrict__ acc,
                           float* __restrict__ out) {
    int lane = threadIdx.x & 63;
    int wave = threadIdx.x >> 6;
    int q    = blockIdx.x * (blockDim.x >> 6) + wave;
    if (q >= N_QUERY) return;

    float a = acc[(size_t)users[q] * EMBED_DIM + lane];
    float b = acc[((size_t)NUM_USERS + items[q]) * EMBED_DIM + lane];
    float p = a * b;

    #pragma unroll
    for (int off = 32; off >= 1; off >>= 1)
        p += __shfl_xor(p, off, 64);

    if (lane == 0)
        out[q] = p * (1.0f / 16.0f);   // (acc/4)·(acc/4)
}

// ---------------------------------------------------------------------------
extern "C" void kernel_launch(void* const* d_in, const int* in_sizes, int n_in,
                              void* d_out, int out_size, void* d_ws, size_t ws_size,
                              hipStream_t stream) {
    const int*   users = (const int*)  d_in[0];
    const int*   items = (const int*)  d_in[1];
    const float* ue    = (const float*)d_in[2];
    const float* ie    = (const float*)d_in[3];
    const int*   rows  = (const int*)  d_in[4];
    const int*   cols  = (const int*)  d_in[5];
    const float* vals  = (const float*)d_in[6];
    float*       out   = (float*)d_out;

    // workspace layout (~155 MB, with aliasing)
    float* acc  = (float*)d_ws;                    // 9.6M f
    float* hA   = acc + NODE_FLOATS;               // 9.6M f
    float* hB   = hA + NODE_FLOATS;                // 9.6M f
    int2*  pair = (int2*)(hB + NODE_FLOATS);       // 4.8M int2

    // rec arrays alias hA/hB (dead until spmm_l1; consumed by scatter2)
    int*   recR = (int*)hA;                        // 16*310016 ints
    int*   recC = recR + NBUCKET * BUCKET_CAP;
    float* recV = (float*)(recC + NBUCKET * BUCKET_CAP);   // ends at 14.88M < 19.2M words

    // cnt8 aliases pair (dead after scan_block; pair written by scatter2 later)
    int*   cnt8 = (int*)pair;                      // 8*150016 ints = 4.8 MB

    int*   row_ptr = (int*)(pair + N_EDGES);       // 150,016 i
    int*   cnt2    = row_ptr + 150016;             // 150,000 i
    int*   flag    = cnt2 + N_NODES;               // 150,000 i
    int*   qn      = flag + N_NODES;               // 1 i
    int*   gcur    = qn + 1;                       // 16 i
    int*   bsums   = gcur + 16;                    // 1,024 i
    int*   qlist   = bsums + 1024;                 // 32,768 i

    int vec_blocks = (int)((NODE_FLOAT4 + 255) / 256);

    // zero cnt8 (pair-aliased) and cnt2+flag+qn (contiguous)
    hipMemsetAsync(cnt8, 0, (size_t)8 * CNT_STRIDE * sizeof(int), stream);
    hipMemsetAsync(cnt2, 0, (size_t)(2 * N_NODES + 1) * sizeof(int), stream);

    init_acc_kernel<<<vec_blocks, 256, 0, stream>>>(
        (const float4*)ue, (const float4*)ie, (float4*)acc, gcur);
    flag_kernel<<<(N_QUERY + 255) / 256, 256, 0, stream>>>(users, items, flag);

    // ---- binning + CSR build ----
    bin_kernel<<<BIN_BLOCKS, 256, 0, stream>>>(rows, cols, vals,
                                               cnt8, gcur, recR, recC, recV);
    scan_block_kernel<<<SCAN_BLOCKS, 256, 0, stream>>>(cnt8, row_ptr, bsums);
    scan_sums_kernel<<<1, 1024, 0, stream>>>(bsums, SCAN_BLOCKS);
    scan_add_kernel<<<SCAN_BLOCKS, 256, 0, stream>>>(row_ptr, bsums);
    scatter2_kernel<<<4096, 256, 0, stream>>>(recR, recC, recV, gcur,
                                              row_ptr, cnt2, pair);

    // ---- SpMM layers ----
    int spmm_blocks = (N_NODES * 64 + 255) / 256;   // one wave per row
    spmm_l1_kernel<<<spmm_blocks, 256, 0, stream>>>(row_ptr, pair, ue, ie, hA, acc);
    spmm_l2_kernel<<<spmm_blocks, 256, 0, stream>>>(row_ptr, pair, hA, hB, acc);

    compact_kernel<<<SCAN_BLOCKS, 256, 0, stream>>>(flag, qlist, qn);

    // layer 3 over at most 2*N_QUERY rows
    int q_blocks = (2 * N_QUERY * 64 + 255) / 256;
    spmm_l3_kernel<<<q_blocks, 256, 0, stream>>>(row_ptr, pair, hB, acc, qlist, qn);

    // ---- epilogue dot products ----
    dot_kernel<<<(N_QUERY + 3) / 4, 256, 0, stream>>>(users, items, acc, out);
}

// Round 6
// 579.991 us; speedup vs baseline: 21.0152x; 1.5040x over previous
//
#include <hip/hip_runtime.h>

#define NUM_USERS 100000
#define NUM_ITEMS 50000
#define EMBED_DIM 64
#define N_NODES   (NUM_USERS + NUM_ITEMS)      // 150000
#define N_EDGES   4800000
#define N_QUERY   16384

#define NODE_FLOATS ((size_t)N_NODES * EMBED_DIM)   // 9,600,000
#define NODE_FLOAT4 (NODE_FLOATS / 4)                // 2,400,000
#define SCAN_BLOCKS ((N_NODES + 255) / 256)          // 586

#define NBUCKET    256
#define BROWS      586                               // 256*586 = 150016 rows
#define BUCKET_CAP 20480                             // mean 18752 + 12.6 sigma
#define BIN_EDGES  8192
#define BIN_THREADS 512
#define BIN_BLOCKS ((N_EDGES + BIN_EDGES - 1) / BIN_EDGES)  // 586

// ---------------------------------------------------------------------------
// init: acc = ego = concat(user_emb, item_emb); init bucket cursors
// ---------------------------------------------------------------------------
__global__ void init_acc_kernel(const float4* __restrict__ ue4,
                                const float4* __restrict__ ie4,
                                float4* __restrict__ acc,
                                int* __restrict__ gcur) {
    if (blockIdx.x == 0 && threadIdx.x < NBUCKET)
        gcur[threadIdx.x] = threadIdx.x * BUCKET_CAP;
    size_t i = (size_t)blockIdx.x * blockDim.x + threadIdx.x;
    if (i >= NODE_FLOAT4) return;
    const size_t user_f4 = (size_t)NUM_USERS * EMBED_DIM / 4;
    acc[i] = (i < user_f4) ? ue4[i] : ie4[i - user_f4];
}

// ---------------------------------------------------------------------------
// flag queried nodes; compact to qlist
// ---------------------------------------------------------------------------
__global__ void flag_kernel(const int* __restrict__ users,
                            const int* __restrict__ items,
                            int* __restrict__ flag) {
    int i = blockIdx.x * blockDim.x + threadIdx.x;
    if (i < N_QUERY) {
        flag[users[i]] = 1;
        flag[NUM_USERS + items[i]] = 1;
    }
}

__global__ void compact_kernel(const int* __restrict__ flag,
                               int* __restrict__ qlist,
                               int* __restrict__ qn) {
    int i = blockIdx.x * blockDim.x + threadIdx.x;
    if (i < N_NODES && flag[i])
        qlist[atomicAdd(qn, 1)] = i;
}

// ---------------------------------------------------------------------------
// bin: single edge read -> 256 row-range buckets. LDS-staged bucket sort,
// coalesced copy-out. Record = int2( (r_local<<18)|col , val_bits ).
// Only 256 global atomics per block (gcur range claims).
// ---------------------------------------------------------------------------
__global__ void __launch_bounds__(BIN_THREADS) bin_kernel(
        const int* __restrict__ rows,
        const int* __restrict__ cols,
        const float* __restrict__ vals,
        int* __restrict__ gcur,
        int2* __restrict__ rec) {
    __shared__ int  lcnt[NBUCKET];
    __shared__ int  lbase[NBUCKET];
    __shared__ int  loff[NBUCKET];
    __shared__ int  lcur[NBUCKET];
    __shared__ int  scan[NBUCKET];
    __shared__ int2 sRec[BIN_EDGES];

    const int tid = threadIdx.x;
    if (tid < NBUCKET) lcnt[tid] = 0;
    __syncthreads();

    const size_t e0 = (size_t)blockIdx.x * BIN_EDGES;

    // pass 1: bucket counts
    for (int k = tid; k < BIN_EDGES; k += BIN_THREADS) {
        size_t e = e0 + k;
        if (e < N_EDGES)
            atomicAdd(&lcnt[rows[e] / BROWS], 1);
    }
    __syncthreads();

    // claim global ranges
    if (tid < NBUCKET) {
        lbase[tid] = atomicAdd(&gcur[tid], lcnt[tid]);
        scan[tid]  = lcnt[tid];
    }
    __syncthreads();
    // parallel inclusive scan (256 entries)
    for (int off = 1; off < NBUCKET; off <<= 1) {
        int tv = (tid < NBUCKET && tid >= off) ? scan[tid - off] : 0;
        __syncthreads();
        if (tid < NBUCKET) scan[tid] += tv;
        __syncthreads();
    }
    if (tid < NBUCKET) {
        loff[tid] = scan[tid] - lcnt[tid];
        lcur[tid] = loff[tid];
    }
    __syncthreads();

    // pass 2: stage records bucket-sorted in LDS (edge arrays L1/L2-hot)
    for (int k = tid; k < BIN_EDGES; k += BIN_THREADS) {
        size_t e = e0 + k;
        if (e < N_EDGES) {
            int r  = rows[e];
            int b  = r / BROWS;
            int rl = r - b * BROWS;
            int slot = atomicAdd(&lcur[b], 1);
            sRec[slot] = make_int2((rl << 18) | cols[e], __float_as_int(vals[e]));
        }
    }
    __syncthreads();

    // copy-out: each of 8 waves handles buckets wv, wv+8, ...
    int wv = tid >> 6, ln = tid & 63;
    for (int b = wv; b < NBUCKET; b += (BIN_THREADS / 64)) {
        int n = lcnt[b], src = loff[b], dst = lbase[b];
        for (int k = ln; k < n; k += 64)
            rec[(size_t)dst + k] = sRec[src + k];
    }
}

// ---------------------------------------------------------------------------
// csr: one block per bucket. LDS hist over 586 local rows -> scan ->
// row_start/row_cnt; LDS-cursor scatter into the bucket's pair slice
// (~150 KB, L2-resident). Zero global atomics.
// ---------------------------------------------------------------------------
__global__ void __launch_bounds__(256) csr_kernel(
        const int2* __restrict__ rec,
        const int* __restrict__ gcur,
        int* __restrict__ row_start,
        int* __restrict__ row_cnt,
        int2* __restrict__ pair) {
    __shared__ int hist[BROWS + 2];
    __shared__ int excl[768];           // 256*3 >= 586
    __shared__ int part[256];

    const int b    = blockIdx.x;
    const int base = b * BUCKET_CAP;
    const int n    = gcur[b] - base;
    const int lo   = b * BROWS;
    const int t    = threadIdx.x;

    for (int j = t; j < BROWS; j += 256) hist[j] = 0;
    __syncthreads();

    // pass 1: local histogram
    for (int i = t; i < n; i += 256)
        atomicAdd(&hist[rec[base + i].x >> 18], 1);
    __syncthreads();

    // exclusive scan of hist[0..BROWS) : 3 entries per thread
    int vloc[3];
    int s0 = 0;
    #pragma unroll
    for (int k = 0; k < 3; ++k) {
        int idx = t * 3 + k;
        int v = (idx < BROWS) ? hist[idx] : 0;
        vloc[k] = s0;
        s0 += v;
    }
    part[t] = s0;
    __syncthreads();
    for (int off = 1; off < 256; off <<= 1) {
        int tv = (t >= off) ? part[t - off] : 0;
        __syncthreads();
        part[t] += tv;
        __syncthreads();
    }
    int pbase = part[t] - s0;
    #pragma unroll
    for (int k = 0; k < 3; ++k) {
        int idx = t * 3 + k;
        if (idx < BROWS) excl[idx] = pbase + vloc[k];
    }
    __syncthreads();

    // emit row_start / row_cnt (global coords into pair[])
    for (int j = t; j < BROWS; j += 256) {
        row_start[lo + j] = base + excl[j];
        row_cnt[lo + j]   = hist[j];
    }
    __syncthreads();

    // pass 2: scatter records; excl doubles as cursor array
    for (int i = t; i < n; i += 256) {
        int2 p = rec[base + i];
        int rl = p.x >> 18;
        int slot = atomicAdd(&excl[rl], 1);
        pair[(size_t)base + slot] = make_int2(p.x & 0x3FFFF, p.y);
    }
}

// ---------------------------------------------------------------------------
// gather-SpMM body: one 64-lane wave per row, lane d owns dim d.
// ---------------------------------------------------------------------------
#define SPMM_BODY(GATHER)                                                     \
    float a = 0.0f;                                                           \
    int i = s;                                                                \
    for (; i + 8 <= e; i += 8) {                                              \
        int2 p0 = pair[i],   p1 = pair[i+1], p2 = pair[i+2], p3 = pair[i+3];  \
        int2 p4 = pair[i+4], p5 = pair[i+5], p6 = pair[i+6], p7 = pair[i+7];  \
        float x0 = GATHER(p0.x); float x1 = GATHER(p1.x);                     \
        float x2 = GATHER(p2.x); float x3 = GATHER(p3.x);                     \
        float x4 = GATHER(p4.x); float x5 = GATHER(p5.x);                     \
        float x6 = GATHER(p6.x); float x7 = GATHER(p7.x);                     \
        a = fmaf(__int_as_float(p0.y), x0, a);                                \
        a = fmaf(__int_as_float(p1.y), x1, a);                                \
        a = fmaf(__int_as_float(p2.y), x2, a);                                \
        a = fmaf(__int_as_float(p3.y), x3, a);                                \
        a = fmaf(__int_as_float(p4.y), x4, a);                                \
        a = fmaf(__int_as_float(p5.y), x5, a);                                \
        a = fmaf(__int_as_float(p6.y), x6, a);                                \
        a = fmaf(__int_as_float(p7.y), x7, a);                                \
    }                                                                         \
    for (; i < e; ++i) {                                                      \
        int2 p = pair[i];                                                     \
        a = fmaf(__int_as_float(p.y), GATHER(p.x), a);                        \
    }

// layer 1: gather from virtual ego = [user_emb ; item_emb]
__global__ void spmm_l1_kernel(const int* __restrict__ row_start,
                               const int* __restrict__ row_cnt,
                               const int2* __restrict__ pair,
                               const float* __restrict__ ue,
                               const float* __restrict__ ie,
                               float* __restrict__ hn,
                               float* __restrict__ acc) {
    int wave = (int)(((size_t)blockIdx.x * blockDim.x + threadIdx.x) >> 6);
    int lane = threadIdx.x & 63;
    if (wave >= N_NODES) return;
    int s = row_start[wave];
    int e = s + row_cnt[wave];

    #define GATHER_EGO(c) \
        (((c) < NUM_USERS) ? ue[(size_t)(c) * EMBED_DIM + lane] \
                           : ie[(size_t)((c) - NUM_USERS) * EMBED_DIM + lane])
    SPMM_BODY(GATHER_EGO)
    #undef GATHER_EGO

    size_t o = (size_t)wave * EMBED_DIM + lane;
    hn[o] = a;
    acc[o] += a;
}

// layer 2: gather from h, all rows
__global__ void spmm_l2_kernel(const int* __restrict__ row_start,
                               const int* __restrict__ row_cnt,
                               const int2* __restrict__ pair,
                               const float* __restrict__ h,
                               float* __restrict__ hn,
                               float* __restrict__ acc) {
    int wave = (int)(((size_t)blockIdx.x * blockDim.x + threadIdx.x) >> 6);
    int lane = threadIdx.x & 63;
    if (wave >= N_NODES) return;
    int s = row_start[wave];
    int e = s + row_cnt[wave];

    #define GATHER_H(c) (h[(size_t)(c) * EMBED_DIM + lane])
    SPMM_BODY(GATHER_H)
    #undef GATHER_H

    size_t o = (size_t)wave * EMBED_DIM + lane;
    hn[o] = a;
    acc[o] += a;
}

// layer 3: only queried rows (qlist), acc-add only
__global__ void spmm_l3_kernel(const int* __restrict__ row_start,
                               const int* __restrict__ row_cnt,
                               const int2* __restrict__ pair,
                               const float* __restrict__ h,
                               float* __restrict__ acc,
                               const int* __restrict__ qlist,
                               const int* __restrict__ qn) {
    int wid  = (int)(((size_t)blockIdx.x * blockDim.x + threadIdx.x) >> 6);
    int lane = threadIdx.x & 63;
    if (wid >= *qn) return;
    int row = qlist[wid];
    int s = row_start[row];
    int e = s + row_cnt[row];

    #define GATHER_H(c) (h[(size_t)(c) * EMBED_DIM + lane])
    SPMM_BODY(GATHER_H)
    #undef GATHER_H

    acc[(size_t)row * EMBED_DIM + lane] += a;
}

// ---------------------------------------------------------------------------
// out[q] = dot(acc[users[q]], acc[NUM_USERS + items[q]]) / 16
// ---------------------------------------------------------------------------
__global__ void dot_kernel(const int* __restrict__ users,
                           const int* __restrict__ items,
                           const float* __restrict__ acc,
                           float* __restrict__ out) {
    int lane = threadIdx.x & 63;
    int wave = threadIdx.x >> 6;
    int q    = blockIdx.x * (blockDim.x >> 6) + wave;
    if (q >= N_QUERY) return;

    float a = acc[(size_t)users[q] * EMBED_DIM + lane];
    float b = acc[((size_t)NUM_USERS + items[q]) * EMBED_DIM + lane];
    float p = a * b;

    #pragma unroll
    for (int off = 32; off >= 1; off >>= 1)
        p += __shfl_xor(p, off, 64);

    if (lane == 0)
        out[q] = p * (1.0f / 16.0f);   // (acc/4)·(acc/4)
}

// ---------------------------------------------------------------------------
extern "C" void kernel_launch(void* const* d_in, const int* in_sizes, int n_in,
                              void* d_out, int out_size, void* d_ws, size_t ws_size,
                              hipStream_t stream) {
    const int*   users = (const int*)  d_in[0];
    const int*   items = (const int*)  d_in[1];
    const float* ue    = (const float*)d_in[2];
    const float* ie    = (const float*)d_in[3];
    const int*   rows  = (const int*)  d_in[4];
    const int*   cols  = (const int*)  d_in[5];
    const float* vals  = (const float*)d_in[6];
    float*       out   = (float*)d_out;

    const size_t REC_N = (size_t)NBUCKET * BUCKET_CAP;   // 5,242,880

    // workspace layout (~159 MB, with aliasing)
    float* acc  = (float*)d_ws;                    // 9.6M f
    float* hA   = acc + NODE_FLOATS;               // 9.6M f
    float* hB   = hA + NODE_FLOATS;                // 9.6M f
    int2*  pair = (int2*)(hB + NODE_FLOATS);       // REC_N int2 (41.9 MB)

    // rec aliases hA/hB (dead until spmm_l1; consumed by csr_kernel)
    int2*  rec  = (int2*)hA;                       // REC_N int2

    int* row_start = (int*)(pair + REC_N);         // 150,016 i
    int* row_cnt   = row_start + 150016;           // 150,016 i
    int* flag      = row_cnt + 150016;             // 150,000 i
    int* qn        = flag + N_NODES;               // 1 i
    int* gcur      = qn + 1;                       // 256 i
    int* qlist     = gcur + NBUCKET;               // 32,768 i

    int vec_blocks = (int)((NODE_FLOAT4 + 255) / 256);

    // zero flag + qn (contiguous)
    hipMemsetAsync(flag, 0, (size_t)(N_NODES + 1) * sizeof(int), stream);

    init_acc_kernel<<<vec_blocks, 256, 0, stream>>>(
        (const float4*)ue, (const float4*)ie, (float4*)acc, gcur);
    flag_kernel<<<(N_QUERY + 255) / 256, 256, 0, stream>>>(users, items, flag);

    // ---- CSR build: bin (bucket sort) + per-bucket LDS CSR ----
    bin_kernel<<<BIN_BLOCKS, BIN_THREADS, 0, stream>>>(rows, cols, vals, gcur, rec);
    csr_kernel<<<NBUCKET, 256, 0, stream>>>(rec, gcur, row_start, row_cnt, pair);

    // ---- SpMM layers ----
    int spmm_blocks = (N_NODES * 64 + 255) / 256;   // one wave per row
    spmm_l1_kernel<<<spmm_blocks, 256, 0, stream>>>(row_start, row_cnt, pair, ue, ie, hA, acc);
    spmm_l2_kernel<<<spmm_blocks, 256, 0, stream>>>(row_start, row_cnt, pair, hA, hB, acc);

    compact_kernel<<<SCAN_BLOCKS, 256, 0, stream>>>(flag, qlist, qn);

    // layer 3 over at most 2*N_QUERY rows
    int q_blocks = (2 * N_QUERY * 64 + 255) / 256;
    spmm_l3_kernel<<<q_blocks, 256, 0, stream>>>(row_start, row_cnt, pair, hB, acc, qlist, qn);

    // ---- epilogue dot products ----
    dot_kernel<<<(N_QUERY + 3) / 4, 256, 0, stream>>>(users, items, acc, out);
}

// Round 8
// 561.614 us; speedup vs baseline: 21.7028x; 1.0327x over previous
//
#include <hip/hip_runtime.h>

#define NUM_USERS 100000
#define NUM_ITEMS 50000
#define EMBED_DIM 64
#define N_NODES   (NUM_USERS + NUM_ITEMS)      // 150000
#define N_EDGES   4800000
#define N_QUERY   16384

#define NODE_FLOATS ((size_t)N_NODES * EMBED_DIM)   // 9,600,000
#define NODE_FLOAT4 (NODE_FLOATS / 4)                // 2,400,000
#define SCAN_BLOCKS ((N_NODES + 255) / 256)          // 586

#define NBUCKET    256
#define BROWS      586                               // 256*586 = 150016 rows
#define BUCKET_CAP 20480
#define BIN_EDGES  8192
#define BIN_THREADS 512
#define BIN_BLOCKS ((N_EDGES + BIN_EDGES - 1) / BIN_EDGES)  // 586

// ---------------------------------------------------------------------------
// init: acc = ego = concat(user_emb, item_emb); init bucket cursors
// ---------------------------------------------------------------------------
__global__ void init_acc_kernel(const float4* __restrict__ ue4,
                                const float4* __restrict__ ie4,
                                float4* __restrict__ acc,
                                int* __restrict__ gcur) {
    if (blockIdx.x == 0 && threadIdx.x < NBUCKET)
        gcur[threadIdx.x] = threadIdx.x * BUCKET_CAP;
    size_t i = (size_t)blockIdx.x * blockDim.x + threadIdx.x;
    if (i >= NODE_FLOAT4) return;
    const size_t user_f4 = (size_t)NUM_USERS * EMBED_DIM / 4;
    acc[i] = (i < user_f4) ? ue4[i] : ie4[i - user_f4];
}

// ---------------------------------------------------------------------------
// flag queried nodes; compact to qlist
// ---------------------------------------------------------------------------
__global__ void flag_kernel(const int* __restrict__ users,
                            const int* __restrict__ items,
                            int* __restrict__ flag) {
    int i = blockIdx.x * blockDim.x + threadIdx.x;
    if (i < N_QUERY) {
        flag[users[i]] = 1;
        flag[NUM_USERS + items[i]] = 1;
    }
}

__global__ void compact_kernel(const int* __restrict__ flag,
                               int* __restrict__ qlist,
                               int* __restrict__ qn) {
    int i = blockIdx.x * blockDim.x + threadIdx.x;
    if (i < N_NODES && flag[i])
        qlist[atomicAdd(qn, 1)] = i;
}

// ---------------------------------------------------------------------------
// bin: single edge read -> 256 row-range buckets. LDS-staged bucket sort,
// coalesced copy-out. Record = int2( (r_local<<18)|col , val_bits ).
// ---------------------------------------------------------------------------
__global__ void __launch_bounds__(BIN_THREADS) bin_kernel(
        const int* __restrict__ rows,
        const int* __restrict__ cols,
        const float* __restrict__ vals,
        int* __restrict__ gcur,
        int2* __restrict__ rec) {
    __shared__ int  lcnt[NBUCKET];
    __shared__ int  lbase[NBUCKET];
    __shared__ int  loff[NBUCKET];
    __shared__ int  lcur[NBUCKET];
    __shared__ int  scan[NBUCKET];
    __shared__ int2 sRec[BIN_EDGES];

    const int tid = threadIdx.x;
    if (tid < NBUCKET) lcnt[tid] = 0;
    __syncthreads();

    const size_t e0 = (size_t)blockIdx.x * BIN_EDGES;

    for (int k = tid; k < BIN_EDGES; k += BIN_THREADS) {
        size_t e = e0 + k;
        if (e < N_EDGES)
            atomicAdd(&lcnt[rows[e] / BROWS], 1);
    }
    __syncthreads();

    if (tid < NBUCKET) {
        lbase[tid] = atomicAdd(&gcur[tid], lcnt[tid]);
        scan[tid]  = lcnt[tid];
    }
    __syncthreads();
    for (int off = 1; off < NBUCKET; off <<= 1) {
        int tv = (tid < NBUCKET && tid >= off) ? scan[tid - off] : 0;
        __syncthreads();
        if (tid < NBUCKET) scan[tid] += tv;
        __syncthreads();
    }
    if (tid < NBUCKET) {
        loff[tid] = scan[tid] - lcnt[tid];
        lcur[tid] = loff[tid];
    }
    __syncthreads();

    for (int k = tid; k < BIN_EDGES; k += BIN_THREADS) {
        size_t e = e0 + k;
        if (e < N_EDGES) {
            int r  = rows[e];
            int b  = r / BROWS;
            int rl = r - b * BROWS;
            int slot = atomicAdd(&lcur[b], 1);
            sRec[slot] = make_int2((rl << 18) | cols[e], __float_as_int(vals[e]));
        }
    }
    __syncthreads();

    int wv = tid >> 6, ln = tid & 63;
    for (int b = wv; b < NBUCKET; b += (BIN_THREADS / 64)) {
        int n = lcnt[b], src = loff[b], dst = lbase[b];
        for (int k = ln; k < n; k += 64)
            rec[(size_t)dst + k] = sRec[src + k];
    }
}

// ---------------------------------------------------------------------------
// csr: one block per bucket. LDS hist over 586 local rows -> scan ->
// row_start/row_cnt; LDS-cursor scatter into the bucket's pair slice.
// ---------------------------------------------------------------------------
__global__ void __launch_bounds__(256) csr_kernel(
        const int2* __restrict__ rec,
        const int* __restrict__ gcur,
        int* __restrict__ row_start,
        int* __restrict__ row_cnt,
        int2* __restrict__ pair) {
    __shared__ int hist[BROWS + 2];
    __shared__ int excl[768];
    __shared__ int part[256];

    const int b    = blockIdx.x;
    const int base = b * BUCKET_CAP;
    const int n    = gcur[b] - base;
    const int lo   = b * BROWS;
    const int t    = threadIdx.x;

    for (int j = t; j < BROWS; j += 256) hist[j] = 0;
    __syncthreads();

    for (int i = t; i < n; i += 256)
        atomicAdd(&hist[rec[base + i].x >> 18], 1);
    __syncthreads();

    int vloc[3];
    int s0 = 0;
    #pragma unroll
    for (int k = 0; k < 3; ++k) {
        int idx = t * 3 + k;
        int v = (idx < BROWS) ? hist[idx] : 0;
        vloc[k] = s0;
        s0 += v;
    }
    part[t] = s0;
    __syncthreads();
    for (int off = 1; off < 256; off <<= 1) {
        int tv = (t >= off) ? part[t - off] : 0;
        __syncthreads();
        part[t] += tv;
        __syncthreads();
    }
    int pbase = part[t] - s0;
    #pragma unroll
    for (int k = 0; k < 3; ++k) {
        int idx = t * 3 + k;
        if (idx < BROWS) excl[idx] = pbase + vloc[k];
    }
    __syncthreads();

    for (int j = t; j < BROWS; j += 256) {
        row_start[lo + j] = base + excl[j];
        row_cnt[lo + j]   = hist[j];
    }
    __syncthreads();

    for (int i = t; i < n; i += 256) {
        int2 p = rec[base + i];
        int rl = p.x >> 18;
        int slot = atomicAdd(&excl[rl], 1);
        pair[(size_t)base + slot] = make_int2(p.x & 0x3FFFF, p.y);
    }
}

// ---------------------------------------------------------------------------
// gather-SpMM body, 4-edges-per-instruction layout:
//   lane = g*16 + q  (g = edge sub-group 0..3, q = dim quad 0..15)
//   per step: group g gathers float4 of h[col(i+g)][4q..4q+3]  (dwordx4)
//   end: reduce float4 over groups via shfl_xor(32,16); lanes 0..15 hold row.
// GATHER4(c) must return float4 = h[c][4q..4q+3].
// NOTE: macro params must not collide with float4 member names (.x/.y/.z/.w).
// ---------------------------------------------------------------------------
#define FMA4(V_, X_, A_) \
    A_.x = fmaf(V_, X_.x, A_.x); A_.y = fmaf(V_, X_.y, A_.y); \
    A_.z = fmaf(V_, X_.z, A_.z); A_.w = fmaf(V_, X_.w, A_.w);

#define SPMM_BODY4(GATHER4)                                                   \
    float4 acc_v = make_float4(0.f, 0.f, 0.f, 0.f);                           \
    int i = s;                                                                \
    for (; i + 8 <= e; i += 8) {                                              \
        int2 pA = pair[i + g];                                                \
        int2 pB = pair[i + 4 + g];                                            \
        float4 gA = GATHER4(pA.x);                                            \
        float4 gB = GATHER4(pB.x);                                            \
        float vA = __int_as_float(pA.y);                                      \
        float vB = __int_as_float(pB.y);                                      \
        FMA4(vA, gA, acc_v)                                                   \
        FMA4(vB, gB, acc_v)                                                   \
    }                                                                         \
    if (i + 4 <= e) {                                                         \
        int2 pC = pair[i + g];                                                \
        float4 gC = GATHER4(pC.x);                                            \
        float vC = __int_as_float(pC.y);                                      \
        FMA4(vC, gC, acc_v)                                                   \
        i += 4;                                                               \
    }                                                                         \
    if (i < e) {                                                              \
        int idx = i + g;                                                      \
        int2 pD = pair[(idx < e) ? idx : (e - 1)];                            \
        float vD = (idx < e) ? __int_as_float(pD.y) : 0.0f;                   \
        float4 gD = GATHER4(pD.x);                                            \
        FMA4(vD, gD, acc_v)                                                   \
    }                                                                         \
    acc_v.x += __shfl_xor(acc_v.x, 32, 64);                                   \
    acc_v.y += __shfl_xor(acc_v.y, 32, 64);                                   \
    acc_v.z += __shfl_xor(acc_v.z, 32, 64);                                   \
    acc_v.w += __shfl_xor(acc_v.w, 32, 64);                                   \
    acc_v.x += __shfl_xor(acc_v.x, 16, 64);                                   \
    acc_v.y += __shfl_xor(acc_v.y, 16, 64);                                   \
    acc_v.z += __shfl_xor(acc_v.z, 16, 64);                                   \
    acc_v.w += __shfl_xor(acc_v.w, 16, 64);

// layer 1: gather from virtual ego = [user_emb ; item_emb]
__global__ void spmm_l1_kernel(const int* __restrict__ row_start,
                               const int* __restrict__ row_cnt,
                               const int2* __restrict__ pair,
                               const float4* __restrict__ ue4,
                               const float4* __restrict__ ie4,
                               float4* __restrict__ hn4,
                               float4* __restrict__ acc4) {
    int wave = (int)(((size_t)blockIdx.x * blockDim.x + threadIdx.x) >> 6);
    int lane = threadIdx.x & 63;
    int g = lane >> 4, q = lane & 15;
    if (wave >= N_NODES) return;
    int s = row_start[wave];
    int e = s + row_cnt[wave];

    #define GATHER4_EGO(c) \
        (((c) < NUM_USERS) ? ue4[(size_t)(c) * 16 + q] \
                           : ie4[(size_t)((c) - NUM_USERS) * 16 + q])
    SPMM_BODY4(GATHER4_EGO)
    #undef GATHER4_EGO

    if (lane < 16) {
        size_t o = (size_t)wave * 16 + q;
        hn4[o] = acc_v;
        float4 t = acc4[o];
        t.x += acc_v.x; t.y += acc_v.y; t.z += acc_v.z; t.w += acc_v.w;
        acc4[o] = t;
    }
}

// layer 2: gather from h
__global__ void spmm_l2_kernel(const int* __restrict__ row_start,
                               const int* __restrict__ row_cnt,
                               const int2* __restrict__ pair,
                               const float4* __restrict__ h4,
                               float4* __restrict__ hn4,
                               float4* __restrict__ acc4) {
    int wave = (int)(((size_t)blockIdx.x * blockDim.x + threadIdx.x) >> 6);
    int lane = threadIdx.x & 63;
    int g = lane >> 4, q = lane & 15;
    if (wave >= N_NODES) return;
    int s = row_start[wave];
    int e = s + row_cnt[wave];

    #define GATHER4_H(c) (h4[(size_t)(c) * 16 + q])
    SPMM_BODY4(GATHER4_H)
    #undef GATHER4_H

    if (lane < 16) {
        size_t o = (size_t)wave * 16 + q;
        hn4[o] = acc_v;
        float4 t = acc4[o];
        t.x += acc_v.x; t.y += acc_v.y; t.z += acc_v.z; t.w += acc_v.w;
        acc4[o] = t;
    }
}

// layer 3: only queried rows (qlist), acc-add only
__global__ void spmm_l3_kernel(const int* __restrict__ row_start,
                               const int* __restrict__ row_cnt,
                               const int2* __restrict__ pair,
                               const float4* __restrict__ h4,
                               float4* __restrict__ acc4,
                               const int* __restrict__ qlist,
                               const int* __restrict__ qn) {
    int wid  = (int)(((size_t)blockIdx.x * blockDim.x + threadIdx.x) >> 6);
    int lane = threadIdx.x & 63;
    int g = lane >> 4, q = lane & 15;
    if (wid >= *qn) return;
    int row = qlist[wid];
    int s = row_start[row];
    int e = s + row_cnt[row];

    #define GATHER4_H(c) (h4[(size_t)(c) * 16 + q])
    SPMM_BODY4(GATHER4_H)
    #undef GATHER4_H

    if (lane < 16) {
        size_t o = (size_t)row * 16 + q;
        float4 t = acc4[o];
        t.x += acc_v.x; t.y += acc_v.y; t.z += acc_v.z; t.w += acc_v.w;
        acc4[o] = t;
    }
}

// ---------------------------------------------------------------------------
// out[q] = dot(acc[users[q]], acc[NUM_USERS + items[q]]) / 16
// ---------------------------------------------------------------------------
__global__ void dot_kernel(const int* __restrict__ users,
                           const int* __restrict__ items,
                           const float* __restrict__ acc,
                           float* __restrict__ out) {
    int lane = threadIdx.x & 63;
    int wave = threadIdx.x >> 6;
    int q    = blockIdx.x * (blockDim.x >> 6) + wave;
    if (q >= N_QUERY) return;

    float a = acc[(size_t)users[q] * EMBED_DIM + lane];
    float b = acc[((size_t)NUM_USERS + items[q]) * EMBED_DIM + lane];
    float p = a * b;

    #pragma unroll
    for (int off = 32; off >= 1; off >>= 1)
        p += __shfl_xor(p, off, 64);

    if (lane == 0)
        out[q] = p * (1.0f / 16.0f);   // (acc/4)·(acc/4)
}

// ---------------------------------------------------------------------------
extern "C" void kernel_launch(void* const* d_in, const int* in_sizes, int n_in,
                              void* d_out, int out_size, void* d_ws, size_t ws_size,
                              hipStream_t stream) {
    const int*   users = (const int*)  d_in[0];
    const int*   items = (const int*)  d_in[1];
    const float* ue    = (const float*)d_in[2];
    const float* ie    = (const float*)d_in[3];
    const int*   rows  = (const int*)  d_in[4];
    const int*   cols  = (const int*)  d_in[5];
    const float* vals  = (const float*)d_in[6];
    float*       out   = (float*)d_out;

    const size_t REC_N = (size_t)NBUCKET * BUCKET_CAP;   // 5,242,880

    float* acc  = (float*)d_ws;                    // 9.6M f
    float* hA   = acc + NODE_FLOATS;               // 9.6M f
    float* hB   = hA + NODE_FLOATS;                // 9.6M f
    int2*  pair = (int2*)(hB + NODE_FLOATS);       // REC_N int2 (41.9 MB)

    int2*  rec  = (int2*)hA;                       // aliases hA/hB (dead until l1)

    int* row_start = (int*)(pair + REC_N);         // 150,016 i
    int* row_cnt   = row_start + 150016;           // 150,016 i
    int* flag      = row_cnt + 150016;             // 150,000 i
    int* qn        = flag + N_NODES;               // 1 i
    int* gcur      = qn + 1;                       // 256 i
    int* qlist     = gcur + NBUCKET;               // 32,768 i

    int vec_blocks = (int)((NODE_FLOAT4 + 255) / 256);

    (void)hipMemsetAsync(flag, 0, (size_t)(N_NODES + 1) * sizeof(int), stream);

    init_acc_kernel<<<vec_blocks, 256, 0, stream>>>(
        (const float4*)ue, (const float4*)ie, (float4*)acc, gcur);
    flag_kernel<<<(N_QUERY + 255) / 256, 256, 0, stream>>>(users, items, flag);

    bin_kernel<<<BIN_BLOCKS, BIN_THREADS, 0, stream>>>(rows, cols, vals, gcur, rec);
    csr_kernel<<<NBUCKET, 256, 0, stream>>>(rec, gcur, row_start, row_cnt, pair);

    int spmm_blocks = (N_NODES * 64 + 255) / 256;
    spmm_l1_kernel<<<spmm_blocks, 256, 0, stream>>>(row_start, row_cnt, pair,
        (const float4*)ue, (const float4*)ie, (float4*)hA, (float4*)acc);
    spmm_l2_kernel<<<spmm_blocks, 256, 0, stream>>>(row_start, row_cnt, pair,
        (const float4*)hA, (float4*)hB, (float4*)acc);

    compact_kernel<<<SCAN_BLOCKS, 256, 0, stream>>>(flag, qlist, qn);

    int q_blocks = (2 * N_QUERY * 64 + 255) / 256;
    spmm_l3_kernel<<<q_blocks, 256, 0, stream>>>(row_start, row_cnt, pair,
        (const float4*)hB, (float4*)acc, qlist, qn);

    dot_kernel<<<(N_QUERY + 3) / 4, 256, 0, stream>>>(users, items, acc, out);
}

// Round 9
// 396.839 us; speedup vs baseline: 30.7143x; 1.4152x over previous
//
#include <hip/hip_runtime.h>

#define NUM_USERS 100000
#define NUM_ITEMS 50000
#define EMBED_DIM 64
#define N_NODES   (NUM_USERS + NUM_ITEMS)      // 150000
#define N_EDGES   4800000
#define N_QUERY   16384

#define NODE_FLOATS ((size_t)N_NODES * EMBED_DIM)   // 9,600,000
#define NODE_FLOAT4 (NODE_FLOATS / 4)                // 2,400,000
#define SCAN_BLOCKS ((N_NODES + 255) / 256)          // 586

#define NBUCKET    256
#define BROWS      586                               // 256*586 = 150016 rows
#define BUCKET_CAP 20480
#define BIN_EDGES  8192
#define BIN_THREADS 512
#define BIN_BLOCKS ((N_EDGES + BIN_EDGES - 1) / BIN_EDGES)  // 586

// ---------------------------------------------------------------------------
// bf16 pack/unpack helpers (RNE)
// ---------------------------------------------------------------------------
__device__ __forceinline__ float4 bf2f4(uint2 u) {
    float4 f;
    f.x = __uint_as_float(u.x << 16);
    f.y = __uint_as_float(u.x & 0xFFFF0000u);
    f.z = __uint_as_float(u.y << 16);
    f.w = __uint_as_float(u.y & 0xFFFF0000u);
    return f;
}
__device__ __forceinline__ unsigned rne_bf(float f) {
    unsigned b = __float_as_uint(f);
    return (b + 0x7FFFu + ((b >> 16) & 1u)) >> 16;
}
__device__ __forceinline__ uint2 f42bf(float4 f) {
    uint2 u;
    u.x = rne_bf(f.x) | (rne_bf(f.y) << 16);
    u.y = rne_bf(f.z) | (rne_bf(f.w) << 16);
    return u;
}
__device__ __forceinline__ void fma4v(float v, float4 xv, float4& av) {
    av.x = fmaf(v, xv.x, av.x);
    av.y = fmaf(v, xv.y, av.y);
    av.z = fmaf(v, xv.z, av.z);
    av.w = fmaf(v, xv.w, av.w);
}

// ---------------------------------------------------------------------------
// init: acc = ego fp32; init bucket cursors
// ---------------------------------------------------------------------------
__global__ void init_acc_kernel(const float4* __restrict__ ue4,
                                const float4* __restrict__ ie4,
                                float4* __restrict__ acc,
                                int* __restrict__ gcur) {
    if (blockIdx.x == 0 && threadIdx.x < NBUCKET)
        gcur[threadIdx.x] = threadIdx.x * BUCKET_CAP;
    size_t i = (size_t)blockIdx.x * blockDim.x + threadIdx.x;
    if (i >= NODE_FLOAT4) return;
    const size_t user_f4 = (size_t)NUM_USERS * EMBED_DIM / 4;
    acc[i] = (i < user_f4) ? ue4[i] : ie4[i - user_f4];
}

// ego_bf = bf16(concat(ue, ie)) — runs AFTER csr (overwrites rec region)
__global__ void ego_bf_kernel(const float4* __restrict__ ue4,
                              const float4* __restrict__ ie4,
                              uint2* __restrict__ ego) {
    size_t i = (size_t)blockIdx.x * blockDim.x + threadIdx.x;
    if (i >= NODE_FLOAT4) return;
    const size_t user_f4 = (size_t)NUM_USERS * EMBED_DIM / 4;
    float4 v = (i < user_f4) ? ue4[i] : ie4[i - user_f4];
    ego[i] = f42bf(v);
}

// ---------------------------------------------------------------------------
// flag queried nodes; compact to qlist
// ---------------------------------------------------------------------------
__global__ void flag_kernel(const int* __restrict__ users,
                            const int* __restrict__ items,
                            int* __restrict__ flag) {
    int i = blockIdx.x * blockDim.x + threadIdx.x;
    if (i < N_QUERY) {
        flag[users[i]] = 1;
        flag[NUM_USERS + items[i]] = 1;
    }
}

__global__ void compact_kernel(const int* __restrict__ flag,
                               int* __restrict__ qlist,
                               int* __restrict__ qn) {
    int i = blockIdx.x * blockDim.x + threadIdx.x;
    if (i < N_NODES && flag[i])
        qlist[atomicAdd(qn, 1)] = i;
}

// ---------------------------------------------------------------------------
// bin: single edge read -> 256 row-range buckets (LDS-staged, coalesced out)
// ---------------------------------------------------------------------------
__global__ void __launch_bounds__(BIN_THREADS) bin_kernel(
        const int* __restrict__ rows,
        const int* __restrict__ cols,
        const float* __restrict__ vals,
        int* __restrict__ gcur,
        int2* __restrict__ rec) {
    __shared__ int  lcnt[NBUCKET];
    __shared__ int  lbase[NBUCKET];
    __shared__ int  loff[NBUCKET];
    __shared__ int  lcur[NBUCKET];
    __shared__ int  scan[NBUCKET];
    __shared__ int2 sRec[BIN_EDGES];

    const int tid = threadIdx.x;
    if (tid < NBUCKET) lcnt[tid] = 0;
    __syncthreads();

    const size_t e0 = (size_t)blockIdx.x * BIN_EDGES;

    for (int k = tid; k < BIN_EDGES; k += BIN_THREADS) {
        size_t e = e0 + k;
        if (e < N_EDGES)
            atomicAdd(&lcnt[rows[e] / BROWS], 1);
    }
    __syncthreads();

    if (tid < NBUCKET) {
        lbase[tid] = atomicAdd(&gcur[tid], lcnt[tid]);
        scan[tid]  = lcnt[tid];
    }
    __syncthreads();
    for (int off = 1; off < NBUCKET; off <<= 1) {
        int tv = (tid < NBUCKET && tid >= off) ? scan[tid - off] : 0;
        __syncthreads();
        if (tid < NBUCKET) scan[tid] += tv;
        __syncthreads();
    }
    if (tid < NBUCKET) {
        loff[tid] = scan[tid] - lcnt[tid];
        lcur[tid] = loff[tid];
    }
    __syncthreads();

    for (int k = tid; k < BIN_EDGES; k += BIN_THREADS) {
        size_t e = e0 + k;
        if (e < N_EDGES) {
            int r  = rows[e];
            int b  = r / BROWS;
            int rl = r - b * BROWS;
            int slot = atomicAdd(&lcur[b], 1);
            sRec[slot] = make_int2((rl << 18) | cols[e], __float_as_int(vals[e]));
        }
    }
    __syncthreads();

    int wv = tid >> 6, ln = tid & 63;
    for (int b = wv; b < NBUCKET; b += (BIN_THREADS / 64)) {
        int n = lcnt[b], src = loff[b], dst = lbase[b];
        for (int k = ln; k < n; k += 64)
            rec[(size_t)dst + k] = sRec[src + k];
    }
}

// ---------------------------------------------------------------------------
// csr: one block per bucket; LDS hist+scan -> row_start/row_cnt; LDS-cursor
// scatter into the bucket's pair slice.
// ---------------------------------------------------------------------------
__global__ void __launch_bounds__(256) csr_kernel(
        const int2* __restrict__ rec,
        const int* __restrict__ gcur,
        int* __restrict__ row_start,
        int* __restrict__ row_cnt,
        int2* __restrict__ pair) {
    __shared__ int hist[BROWS + 2];
    __shared__ int excl[768];
    __shared__ int part[256];

    const int b    = blockIdx.x;
    const int base = b * BUCKET_CAP;
    const int n    = gcur[b] - base;
    const int lo   = b * BROWS;
    const int t    = threadIdx.x;

    for (int j = t; j < BROWS; j += 256) hist[j] = 0;
    __syncthreads();

    for (int i = t; i < n; i += 256)
        atomicAdd(&hist[rec[base + i].x >> 18], 1);
    __syncthreads();

    int vloc[3];
    int s0 = 0;
    #pragma unroll
    for (int k = 0; k < 3; ++k) {
        int idx = t * 3 + k;
        int v = (idx < BROWS) ? hist[idx] : 0;
        vloc[k] = s0;
        s0 += v;
    }
    part[t] = s0;
    __syncthreads();
    for (int off = 1; off < 256; off <<= 1) {
        int tv = (t >= off) ? part[t - off] : 0;
        __syncthreads();
        part[t] += tv;
        __syncthreads();
    }
    int pbase = part[t] - s0;
    #pragma unroll
    for (int k = 0; k < 3; ++k) {
        int idx = t * 3 + k;
        if (idx < BROWS) excl[idx] = pbase + vloc[k];
    }
    __syncthreads();

    for (int j = t; j < BROWS; j += 256) {
        row_start[lo + j] = base + excl[j];
        row_cnt[lo + j]   = hist[j];
    }
    __syncthreads();

    for (int i = t; i < n; i += 256) {
        int2 p = rec[base + i];
        int rl = p.x >> 18;
        int slot = atomicAdd(&excl[rl], 1);
        pair[(size_t)base + slot] = make_int2(p.x & 0x3FFFF, p.y);
    }
}

// ---------------------------------------------------------------------------
// gather-SpMM: wave = one row; lane = g*16+q; group g handles edge i+4k+g,
// lane loads uint2 (4 bf16 dims). Unroll 16 -> 4 independent gathers in
// flight. End: reduce over groups via shfl_xor(32,16); lanes 0..15 store.
// ---------------------------------------------------------------------------
template<bool WRITE_HN, bool USE_QLIST>
__global__ void spmm_kernel(const int* __restrict__ row_start,
                            const int* __restrict__ row_cnt,
                            const int2* __restrict__ pair,
                            const uint2* __restrict__ hb,   // bf16 gather src
                            uint2* __restrict__ hn,         // bf16 out (next layer)
                            float4* __restrict__ acc4,      // fp32 accumulate
                            const int* __restrict__ qlist,
                            const int* __restrict__ qn) {
    int wid  = (int)(((size_t)blockIdx.x * blockDim.x + threadIdx.x) >> 6);
    int lane = threadIdx.x & 63;
    int g = lane >> 4, q = lane & 15;

    int row;
    if (USE_QLIST) {
        if (wid >= *qn) return;
        row = qlist[wid];
    } else {
        if (wid >= N_NODES) return;
        row = wid;
    }
    int s = row_start[row];
    int e = s + row_cnt[row];

    float4 av = make_float4(0.f, 0.f, 0.f, 0.f);
    int i = s;
    for (; i + 16 <= e; i += 16) {
        int2 p0 = pair[i + g];
        int2 p1 = pair[i + 4 + g];
        int2 p2 = pair[i + 8 + g];
        int2 p3 = pair[i + 12 + g];
        uint2 u0 = hb[(size_t)p0.x * 16 + q];
        uint2 u1 = hb[(size_t)p1.x * 16 + q];
        uint2 u2 = hb[(size_t)p2.x * 16 + q];
        uint2 u3 = hb[(size_t)p3.x * 16 + q];
        fma4v(__int_as_float(p0.y), bf2f4(u0), av);
        fma4v(__int_as_float(p1.y), bf2f4(u1), av);
        fma4v(__int_as_float(p2.y), bf2f4(u2), av);
        fma4v(__int_as_float(p3.y), bf2f4(u3), av);
    }
    if (i + 8 <= e) {
        int2 p0 = pair[i + g];
        int2 p1 = pair[i + 4 + g];
        uint2 u0 = hb[(size_t)p0.x * 16 + q];
        uint2 u1 = hb[(size_t)p1.x * 16 + q];
        fma4v(__int_as_float(p0.y), bf2f4(u0), av);
        fma4v(__int_as_float(p1.y), bf2f4(u1), av);
        i += 8;
    }
    if (i + 4 <= e) {
        int2 p0 = pair[i + g];
        uint2 u0 = hb[(size_t)p0.x * 16 + q];
        fma4v(__int_as_float(p0.y), bf2f4(u0), av);
        i += 4;
    }
    if (i < e) {
        int idx = i + g;
        int2 pD = pair[(idx < e) ? idx : (e - 1)];
        float vD = (idx < e) ? __int_as_float(pD.y) : 0.0f;
        uint2 uD = hb[(size_t)pD.x * 16 + q];
        fma4v(vD, bf2f4(uD), av);
    }

    av.x += __shfl_xor(av.x, 32, 64);
    av.y += __shfl_xor(av.y, 32, 64);
    av.z += __shfl_xor(av.z, 32, 64);
    av.w += __shfl_xor(av.w, 32, 64);
    av.x += __shfl_xor(av.x, 16, 64);
    av.y += __shfl_xor(av.y, 16, 64);
    av.z += __shfl_xor(av.z, 16, 64);
    av.w += __shfl_xor(av.w, 16, 64);

    if (lane < 16) {
        size_t o = (size_t)row * 16 + q;
        if (WRITE_HN) hn[o] = f42bf(av);
        float4 t = acc4[o];
        t.x += av.x; t.y += av.y; t.z += av.z; t.w += av.w;
        acc4[o] = t;
    }
}

// ---------------------------------------------------------------------------
// out[q] = dot(acc[users[q]], acc[NUM_USERS + items[q]]) / 16
// ---------------------------------------------------------------------------
__global__ void dot_kernel(const int* __restrict__ users,
                           const int* __restrict__ items,
                           const float* __restrict__ acc,
                           float* __restrict__ out) {
    int lane = threadIdx.x & 63;
    int wave = threadIdx.x >> 6;
    int q    = blockIdx.x * (blockDim.x >> 6) + wave;
    if (q >= N_QUERY) return;

    float a = acc[(size_t)users[q] * EMBED_DIM + lane];
    float b = acc[((size_t)NUM_USERS + items[q]) * EMBED_DIM + lane];
    float p = a * b;

    #pragma unroll
    for (int off = 32; off >= 1; off >>= 1)
        p += __shfl_xor(p, off, 64);

    if (lane == 0)
        out[q] = p * (1.0f / 16.0f);   // (acc/4)·(acc/4)
}

// ---------------------------------------------------------------------------
extern "C" void kernel_launch(void* const* d_in, const int* in_sizes, int n_in,
                              void* d_out, int out_size, void* d_ws, size_t ws_size,
                              hipStream_t stream) {
    const int*   users = (const int*)  d_in[0];
    const int*   items = (const int*)  d_in[1];
    const float* ue    = (const float*)d_in[2];
    const float* ie    = (const float*)d_in[3];
    const int*   rows  = (const int*)  d_in[4];
    const int*   cols  = (const int*)  d_in[5];
    const float* vals  = (const float*)d_in[6];
    float*       out   = (float*)d_out;

    const size_t REC_N = (size_t)NBUCKET * BUCKET_CAP;   // 5,242,880

    // workspace layout (~144 MB, with aliasing):
    //   acc (fp32) | X: rec -> {ego_bf, hA_bf} | hB_bf | pair | ints
    float* acc = (float*)d_ws;                          // 9.6M f
    float* X   = acc + NODE_FLOATS;                     // REC_N*2 = 10.49M f
    int2*  rec = (int2*)X;                              // bin/csr phase
    uint2* ego_bf = (uint2*)X;                          // 2.4M uint2 (post-csr)
    uint2* hA_bf  = (uint2*)(X + 4800000);              // 2.4M uint2
    float* afterX = X + REC_N * 2;
    uint2* hB_bf  = (uint2*)afterX;                     // 2.4M uint2
    int2*  pair   = (int2*)(afterX + 4800000);          // REC_N int2

    int* row_start = (int*)(pair + REC_N);              // 150,016 i
    int* row_cnt   = row_start + 150016;                // 150,016 i
    int* flag      = row_cnt + 150016;                  // 150,000 i
    int* qn        = flag + N_NODES;                    // 1 i
    int* gcur      = qn + 1;                            // 256 i
    int* qlist     = gcur + NBUCKET;                    // 32,768 i

    int vec_blocks = (int)((NODE_FLOAT4 + 255) / 256);

    (void)hipMemsetAsync(flag, 0, (size_t)(N_NODES + 1) * sizeof(int), stream);

    init_acc_kernel<<<vec_blocks, 256, 0, stream>>>(
        (const float4*)ue, (const float4*)ie, (float4*)acc, gcur);
    flag_kernel<<<(N_QUERY + 255) / 256, 256, 0, stream>>>(users, items, flag);

    bin_kernel<<<BIN_BLOCKS, BIN_THREADS, 0, stream>>>(rows, cols, vals, gcur, rec);
    csr_kernel<<<NBUCKET, 256, 0, stream>>>(rec, gcur, row_start, row_cnt, pair);

    // rec is now dead -> build bf16 ego in its place
    ego_bf_kernel<<<vec_blocks, 256, 0, stream>>>(
        (const float4*)ue, (const float4*)ie, ego_bf);

    int spmm_blocks = (N_NODES * 64 + 255) / 256;
    spmm_kernel<true, false><<<spmm_blocks, 256, 0, stream>>>(
        row_start, row_cnt, pair, ego_bf, hA_bf, (float4*)acc, nullptr, nullptr);
    spmm_kernel<true, false><<<spmm_blocks, 256, 0, stream>>>(
        row_start, row_cnt, pair, hA_bf, hB_bf, (float4*)acc, nullptr, nullptr);

    compact_kernel<<<SCAN_BLOCKS, 256, 0, stream>>>(flag, qlist, qn);

    int q_blocks = (2 * N_QUERY * 64 + 255) / 256;
    spmm_kernel<false, true><<<q_blocks, 256, 0, stream>>>(
        row_start, row_cnt, pair, hB_bf, nullptr, (float4*)acc, qlist, qn);

    dot_kernel<<<(N_QUERY + 3) / 4, 256, 0, stream>>>(users, items, acc, out);
}

// Round 10
// 364.614 us; speedup vs baseline: 33.4288x; 1.0884x over previous
//
#include <hip/hip_runtime.h>

#define NUM_USERS 100000
#define NUM_ITEMS 50000
#define EMBED_DIM 64
#define N_NODES   (NUM_USERS + NUM_ITEMS)      // 150000
#define N_EDGES   4800000
#define N_QUERY   16384

#define NODE_FLOATS ((size_t)N_NODES * EMBED_DIM)   // 9,600,000
#define NODE_FLOAT4 (NODE_FLOATS / 4)                // 2,400,000
#define SCAN_BLOCKS ((N_NODES + 255) / 256)          // 586

#define NBUCKET    256
#define BROWS      586                               // 256*586 = 150016 rows
#define BUCKET_CAP 20480
#define BIN_EDGES  8192
#define BIN_THREADS 512
#define BIN_BLOCKS ((N_EDGES + BIN_EDGES - 1) / BIN_EDGES)  // 586

// ---------------------------------------------------------------------------
// bf16 pack/unpack helpers (RNE)
// ---------------------------------------------------------------------------
__device__ __forceinline__ float4 bf2f4(uint2 u) {
    float4 f;
    f.x = __uint_as_float(u.x << 16);
    f.y = __uint_as_float(u.x & 0xFFFF0000u);
    f.z = __uint_as_float(u.y << 16);
    f.w = __uint_as_float(u.y & 0xFFFF0000u);
    return f;
}
__device__ __forceinline__ unsigned rne_bf(float f) {
    unsigned b = __float_as_uint(f);
    return (b + 0x7FFFu + ((b >> 16) & 1u)) >> 16;
}
__device__ __forceinline__ uint2 f42bf(float4 f) {
    uint2 u;
    u.x = rne_bf(f.x) | (rne_bf(f.y) << 16);
    u.y = rne_bf(f.z) | (rne_bf(f.w) << 16);
    return u;
}
__device__ __forceinline__ void fma4v(float v, float4 xv, float4& av) {
    av.x = fmaf(v, xv.x, av.x);
    av.y = fmaf(v, xv.y, av.y);
    av.z = fmaf(v, xv.z, av.z);
    av.w = fmaf(v, xv.w, av.w);
}

// ---------------------------------------------------------------------------
// ego_bf = bf16(concat(ue, ie)) — runs AFTER csr (overwrites rec region)
// ---------------------------------------------------------------------------
__global__ void ego_bf_kernel(const float4* __restrict__ ue4,
                              const float4* __restrict__ ie4,
                              uint2* __restrict__ ego) {
    size_t i = (size_t)blockIdx.x * blockDim.x + threadIdx.x;
    if (i >= NODE_FLOAT4) return;
    const size_t user_f4 = (size_t)NUM_USERS * EMBED_DIM / 4;
    float4 v = (i < user_f4) ? ue4[i] : ie4[i - user_f4];
    ego[i] = f42bf(v);
}

// ---------------------------------------------------------------------------
// flag queried nodes (+ init bucket cursors); compact to qlist
// ---------------------------------------------------------------------------
__global__ void flag_kernel(const int* __restrict__ users,
                            const int* __restrict__ items,
                            int* __restrict__ flag,
                            int* __restrict__ gcur) {
    int i = blockIdx.x * blockDim.x + threadIdx.x;
    if (blockIdx.x == 0 && threadIdx.x < NBUCKET)
        gcur[threadIdx.x] = threadIdx.x * BUCKET_CAP;
    if (i < N_QUERY) {
        flag[users[i]] = 1;
        flag[NUM_USERS + items[i]] = 1;
    }
}

__global__ void compact_kernel(const int* __restrict__ flag,
                               int* __restrict__ qlist,
                               int* __restrict__ qn) {
    int i = blockIdx.x * blockDim.x + threadIdx.x;
    if (i < N_NODES && flag[i])
        qlist[atomicAdd(qn, 1)] = i;
}

// ---------------------------------------------------------------------------
// bin: single edge read -> 256 row-range buckets (LDS-staged, coalesced out)
// ---------------------------------------------------------------------------
__global__ void __launch_bounds__(BIN_THREADS) bin_kernel(
        const int* __restrict__ rows,
        const int* __restrict__ cols,
        const float* __restrict__ vals,
        int* __restrict__ gcur,
        int2* __restrict__ rec) {
    __shared__ int  lcnt[NBUCKET];
    __shared__ int  lbase[NBUCKET];
    __shared__ int  loff[NBUCKET];
    __shared__ int  lcur[NBUCKET];
    __shared__ int  scan[NBUCKET];
    __shared__ int2 sRec[BIN_EDGES];

    const int tid = threadIdx.x;
    if (tid < NBUCKET) lcnt[tid] = 0;
    __syncthreads();

    const size_t e0 = (size_t)blockIdx.x * BIN_EDGES;

    for (int k = tid; k < BIN_EDGES; k += BIN_THREADS) {
        size_t e = e0 + k;
        if (e < N_EDGES)
            atomicAdd(&lcnt[rows[e] / BROWS], 1);
    }
    __syncthreads();

    if (tid < NBUCKET) {
        lbase[tid] = atomicAdd(&gcur[tid], lcnt[tid]);
        scan[tid]  = lcnt[tid];
    }
    __syncthreads();
    for (int off = 1; off < NBUCKET; off <<= 1) {
        int tv = (tid < NBUCKET && tid >= off) ? scan[tid - off] : 0;
        __syncthreads();
        if (tid < NBUCKET) scan[tid] += tv;
        __syncthreads();
    }
    if (tid < NBUCKET) {
        loff[tid] = scan[tid] - lcnt[tid];
        lcur[tid] = loff[tid];
    }
    __syncthreads();

    for (int k = tid; k < BIN_EDGES; k += BIN_THREADS) {
        size_t e = e0 + k;
        if (e < N_EDGES) {
            int r  = rows[e];
            int b  = r / BROWS;
            int rl = r - b * BROWS;
            int slot = atomicAdd(&lcur[b], 1);
            sRec[slot] = make_int2((rl << 18) | cols[e], __float_as_int(vals[e]));
        }
    }
    __syncthreads();

    int wv = tid >> 6, ln = tid & 63;
    for (int b = wv; b < NBUCKET; b += (BIN_THREADS / 64)) {
        int n = lcnt[b], src = loff[b], dst = lbase[b];
        for (int k = ln; k < n; k += 64)
            rec[(size_t)dst + k] = sRec[src + k];
    }
}

// ---------------------------------------------------------------------------
// csr: one block per bucket; LDS hist+scan -> row_start/row_cnt; LDS-cursor
// scatter into the bucket's pair slice.
// ---------------------------------------------------------------------------
__global__ void __launch_bounds__(256) csr_kernel(
        const int2* __restrict__ rec,
        const int* __restrict__ gcur,
        int* __restrict__ row_start,
        int* __restrict__ row_cnt,
        int2* __restrict__ pair) {
    __shared__ int hist[BROWS + 2];
    __shared__ int excl[768];
    __shared__ int part[256];

    const int b    = blockIdx.x;
    const int base = b * BUCKET_CAP;
    const int n    = gcur[b] - base;
    const int lo   = b * BROWS;
    const int t    = threadIdx.x;

    for (int j = t; j < BROWS; j += 256) hist[j] = 0;
    __syncthreads();

    for (int i = t; i < n; i += 256)
        atomicAdd(&hist[rec[base + i].x >> 18], 1);
    __syncthreads();

    int vloc[3];
    int s0 = 0;
    #pragma unroll
    for (int k = 0; k < 3; ++k) {
        int idx = t * 3 + k;
        int v = (idx < BROWS) ? hist[idx] : 0;
        vloc[k] = s0;
        s0 += v;
    }
    part[t] = s0;
    __syncthreads();
    for (int off = 1; off < 256; off <<= 1) {
        int tv = (t >= off) ? part[t - off] : 0;
        __syncthreads();
        part[t] += tv;
        __syncthreads();
    }
    int pbase = part[t] - s0;
    #pragma unroll
    for (int k = 0; k < 3; ++k) {
        int idx = t * 3 + k;
        if (idx < BROWS) excl[idx] = pbase + vloc[k];
    }
    __syncthreads();

    for (int j = t; j < BROWS; j += 256) {
        row_start[lo + j] = base + excl[j];
        row_cnt[lo + j]   = hist[j];
    }
    __syncthreads();

    for (int i = t; i < n; i += 256) {
        int2 p = rec[base + i];
        int rl = p.x >> 18;
        int slot = atomicAdd(&excl[rl], 1);
        pair[(size_t)base + slot] = make_int2(p.x & 0x3FFFF, p.y);
    }
}

// ---------------------------------------------------------------------------
// gather core: one 64-lane wave per row; lane = g*16+q; group g handles edge
// i+4k+g; lane loads uint2 (4 bf16 dims). Returns the reduced row float4
// (valid in lanes 0..15 after shfl reduce).
// ---------------------------------------------------------------------------
__device__ __forceinline__ float4 gather_row(int s, int e, int g, int q,
                                             const int2* __restrict__ pair,
                                             const uint2* __restrict__ hb) {
    float4 av = make_float4(0.f, 0.f, 0.f, 0.f);
    int i = s;
    for (; i + 16 <= e; i += 16) {
        int2 p0 = pair[i + g];
        int2 p1 = pair[i + 4 + g];
        int2 p2 = pair[i + 8 + g];
        int2 p3 = pair[i + 12 + g];
        uint2 u0 = hb[(size_t)p0.x * 16 + q];
        uint2 u1 = hb[(size_t)p1.x * 16 + q];
        uint2 u2 = hb[(size_t)p2.x * 16 + q];
        uint2 u3 = hb[(size_t)p3.x * 16 + q];
        fma4v(__int_as_float(p0.y), bf2f4(u0), av);
        fma4v(__int_as_float(p1.y), bf2f4(u1), av);
        fma4v(__int_as_float(p2.y), bf2f4(u2), av);
        fma4v(__int_as_float(p3.y), bf2f4(u3), av);
    }
    if (i + 8 <= e) {
        int2 p0 = pair[i + g];
        int2 p1 = pair[i + 4 + g];
        uint2 u0 = hb[(size_t)p0.x * 16 + q];
        uint2 u1 = hb[(size_t)p1.x * 16 + q];
        fma4v(__int_as_float(p0.y), bf2f4(u0), av);
        fma4v(__int_as_float(p1.y), bf2f4(u1), av);
        i += 8;
    }
    if (i + 4 <= e) {
        int2 p0 = pair[i + g];
        uint2 u0 = hb[(size_t)p0.x * 16 + q];
        fma4v(__int_as_float(p0.y), bf2f4(u0), av);
        i += 4;
    }
    if (i < e) {
        int idx = i + g;
        int2 pD = pair[(idx < e) ? idx : (e - 1)];
        float vD = (idx < e) ? __int_as_float(pD.y) : 0.0f;
        uint2 uD = hb[(size_t)pD.x * 16 + q];
        fma4v(vD, bf2f4(uD), av);
    }
    av.x += __shfl_xor(av.x, 32, 64);
    av.y += __shfl_xor(av.y, 32, 64);
    av.z += __shfl_xor(av.z, 32, 64);
    av.w += __shfl_xor(av.w, 32, 64);
    av.x += __shfl_xor(av.x, 16, 64);
    av.y += __shfl_xor(av.y, 16, 64);
    av.z += __shfl_xor(av.z, 16, 64);
    av.w += __shfl_xor(av.w, 16, 64);
    return av;
}

// ---------------------------------------------------------------------------
// spmm layer: hn = bf16(A * hb)   (no accumulator RMW)
// ---------------------------------------------------------------------------
__global__ void spmm_kernel(const int* __restrict__ row_start,
                            const int* __restrict__ row_cnt,
                            const int2* __restrict__ pair,
                            const uint2* __restrict__ hb,
                            uint2* __restrict__ hn) {
    int wid  = (int)(((size_t)blockIdx.x * blockDim.x + threadIdx.x) >> 6);
    int lane = threadIdx.x & 63;
    int g = lane >> 4, q = lane & 15;
    if (wid >= N_NODES) return;
    int s = row_start[wid];
    int e = s + row_cnt[wid];

    float4 av = gather_row(s, e, g, q, pair, hb);

    if (lane < 16)
        hn[(size_t)wid * 16 + q] = f42bf(av);
}

// ---------------------------------------------------------------------------
// final: for queried rows only — h3 = (A*hB)[row];
// fin[row] = 0.25f * (ego_fp32[row] + hA[row] + hB[row] + h3)
// ---------------------------------------------------------------------------
__global__ void final_kernel(const int* __restrict__ row_start,
                             const int* __restrict__ row_cnt,
                             const int2* __restrict__ pair,
                             const uint2* __restrict__ hB,
                             const uint2* __restrict__ hA,
                             const float4* __restrict__ ue4,
                             const float4* __restrict__ ie4,
                             float4* __restrict__ fin4,
                             const int* __restrict__ qlist,
                             const int* __restrict__ qn) {
    int wid  = (int)(((size_t)blockIdx.x * blockDim.x + threadIdx.x) >> 6);
    int lane = threadIdx.x & 63;
    int g = lane >> 4, q = lane & 15;
    if (wid >= *qn) return;
    int row = qlist[wid];
    int s = row_start[row];
    int e = s + row_cnt[row];

    float4 av = gather_row(s, e, g, q, pair, hB);

    if (lane < 16) {
        size_t o = (size_t)row * 16 + q;
        float4 ego = (row < NUM_USERS)
                   ? ue4[(size_t)row * 16 + q]
                   : ie4[(size_t)(row - NUM_USERS) * 16 + q];
        float4 a1 = bf2f4(hA[o]);
        float4 a2 = bf2f4(hB[o]);
        float4 f;
        f.x = 0.25f * (ego.x + a1.x + a2.x + av.x);
        f.y = 0.25f * (ego.y + a1.y + a2.y + av.y);
        f.z = 0.25f * (ego.z + a1.z + a2.z + av.z);
        f.w = 0.25f * (ego.w + a1.w + a2.w + av.w);
        fin4[o] = f;
    }
}

// ---------------------------------------------------------------------------
// out[q] = dot(fin[users[q]], fin[NUM_USERS + items[q]])   (scale folded)
// ---------------------------------------------------------------------------
__global__ void dot_kernel(const int* __restrict__ users,
                           const int* __restrict__ items,
                           const float* __restrict__ fin,
                           float* __restrict__ out) {
    int lane = threadIdx.x & 63;
    int wave = threadIdx.x >> 6;
    int q    = blockIdx.x * (blockDim.x >> 6) + wave;
    if (q >= N_QUERY) return;

    float a = fin[(size_t)users[q] * EMBED_DIM + lane];
    float b = fin[((size_t)NUM_USERS + items[q]) * EMBED_DIM + lane];
    float p = a * b;

    #pragma unroll
    for (int off = 32; off >= 1; off >>= 1)
        p += __shfl_xor(p, off, 64);

    if (lane == 0)
        out[q] = p;
}

// ---------------------------------------------------------------------------
extern "C" void kernel_launch(void* const* d_in, const int* in_sizes, int n_in,
                              void* d_out, int out_size, void* d_ws, size_t ws_size,
                              hipStream_t stream) {
    const int*   users = (const int*)  d_in[0];
    const int*   items = (const int*)  d_in[1];
    const float* ue    = (const float*)d_in[2];
    const float* ie    = (const float*)d_in[3];
    const int*   rows  = (const int*)  d_in[4];
    const int*   cols  = (const int*)  d_in[5];
    const float* vals  = (const float*)d_in[6];
    float*       out   = (float*)d_out;

    const size_t REC_N = (size_t)NBUCKET * BUCKET_CAP;   // 5,242,880

    // workspace layout (~140 MB):
    //   fin fp32 | ego_bf | hA_bf | hB_bf | pair | ints
    //   rec aliases [ego_bf .. into hB_bf) — dead before those are written
    float* fin    = (float*)d_ws;                        // 9.6M f  (38.4 MB)
    uint2* ego_bf = (uint2*)(fin + NODE_FLOATS);         // 2.4M u2 (19.2 MB)
    uint2* hA_bf  = ego_bf + NODE_FLOAT4;                // 2.4M u2 (19.2 MB)
    uint2* hB_bf  = hA_bf + NODE_FLOAT4;                 // 2.4M u2 (19.2 MB)
    int2*  rec    = (int2*)ego_bf;                       // 41.9 MB (aliased)
    int2*  pair   = (int2*)(hB_bf + NODE_FLOAT4);        // 41.9 MB

    int* row_start = (int*)(pair + REC_N);               // 150,016 i
    int* row_cnt   = row_start + 150016;                 // 150,016 i
    int* flag      = row_cnt + 150016;                   // 150,000 i
    int* qn        = flag + N_NODES;                     // 1 i
    int* gcur      = qn + 1;                             // 256 i
    int* qlist     = gcur + NBUCKET;                     // 32,768 i

    int vec_blocks = (int)((NODE_FLOAT4 + 255) / 256);

    (void)hipMemsetAsync(flag, 0, (size_t)(N_NODES + 1) * sizeof(int), stream);

    flag_kernel<<<(N_QUERY + 255) / 256, 256, 0, stream>>>(users, items, flag, gcur);

    bin_kernel<<<BIN_BLOCKS, BIN_THREADS, 0, stream>>>(rows, cols, vals, gcur, rec);
    csr_kernel<<<NBUCKET, 256, 0, stream>>>(rec, gcur, row_start, row_cnt, pair);

    // rec dead -> build bf16 ego in its place
    ego_bf_kernel<<<vec_blocks, 256, 0, stream>>>(
        (const float4*)ue, (const float4*)ie, ego_bf);

    int spmm_blocks = (N_NODES * 64 + 255) / 256;
    spmm_kernel<<<spmm_blocks, 256, 0, stream>>>(row_start, row_cnt, pair, ego_bf, hA_bf);
    spmm_kernel<<<spmm_blocks, 256, 0, stream>>>(row_start, row_cnt, pair, hA_bf, hB_bf);

    compact_kernel<<<SCAN_BLOCKS, 256, 0, stream>>>(flag, qlist, qn);

    int q_blocks = (2 * N_QUERY * 64 + 255) / 256;
    final_kernel<<<q_blocks, 256, 0, stream>>>(row_start, row_cnt, pair,
        hB_bf, hA_bf, (const float4*)ue, (const float4*)ie, (float4*)fin, qlist, qn);

    dot_kernel<<<(N_QUERY + 3) / 4, 256, 0, stream>>>(users, items, fin, out);
}

// Round 11
// 335.616 us; speedup vs baseline: 36.3171x; 1.0864x over previous
//
#include <hip/hip_runtime.h>

#define NUM_USERS 100000
#define NUM_ITEMS 50000
#define EMBED_DIM 64
#define N_NODES   (NUM_USERS + NUM_ITEMS)      // 150000
#define N_EDGES   4800000
#define N_QUERY   16384

#define NODE_FLOATS ((size_t)N_NODES * EMBED_DIM)   // 9,600,000
#define NODE_FLOAT4 (NODE_FLOATS / 4)                // 2,400,000

#define NBUCKET    256
#define BROWS      586                               // 256*586 = 150016 rows
#define BUCKET_CAP 20480
#define BIN_EDGES  8192
#define BIN_THREADS 512
#define BIN_BLOCKS ((N_EDGES + BIN_EDGES - 1) / BIN_EDGES)  // 586

// ---------------------------------------------------------------------------
// bf16 pack/unpack helpers (RNE)
// ---------------------------------------------------------------------------
__device__ __forceinline__ float4 bf2f4(uint2 u) {
    float4 f;
    f.x = __uint_as_float(u.x << 16);
    f.y = __uint_as_float(u.x & 0xFFFF0000u);
    f.z = __uint_as_float(u.y << 16);
    f.w = __uint_as_float(u.y & 0xFFFF0000u);
    return f;
}
__device__ __forceinline__ unsigned rne_bf(float f) {
    unsigned b = __float_as_uint(f);
    return (b + 0x7FFFu + ((b >> 16) & 1u)) >> 16;
}
__device__ __forceinline__ uint2 f42bf(float4 f) {
    uint2 u;
    u.x = rne_bf(f.x) | (rne_bf(f.y) << 16);
    u.y = rne_bf(f.z) | (rne_bf(f.w) << 16);
    return u;
}
__device__ __forceinline__ void fma4v(float v, float4 xv, float4& av) {
    av.x = fmaf(v, xv.x, av.x);
    av.y = fmaf(v, xv.y, av.y);
    av.z = fmaf(v, xv.z, av.z);
    av.w = fmaf(v, xv.w, av.w);
}

// ---------------------------------------------------------------------------
// init bucket cursors
// ---------------------------------------------------------------------------
__global__ void init_gcur_kernel(int* __restrict__ gcur) {
    if (threadIdx.x < NBUCKET)
        gcur[threadIdx.x] = threadIdx.x * BUCKET_CAP;
}

// ego_bf = bf16(concat(ue, ie)) — runs AFTER csr (overwrites rec region)
__global__ void ego_bf_kernel(const float4* __restrict__ ue4,
                              const float4* __restrict__ ie4,
                              uint2* __restrict__ ego) {
    size_t i = (size_t)blockIdx.x * blockDim.x + threadIdx.x;
    if (i >= NODE_FLOAT4) return;
    const size_t user_f4 = (size_t)NUM_USERS * EMBED_DIM / 4;
    float4 v = (i < user_f4) ? ue4[i] : ie4[i - user_f4];
    ego[i] = f42bf(v);
}

// ---------------------------------------------------------------------------
// bin: single edge read -> 256 row-range buckets (LDS-staged, coalesced out)
// ---------------------------------------------------------------------------
__global__ void __launch_bounds__(BIN_THREADS) bin_kernel(
        const int* __restrict__ rows,
        const int* __restrict__ cols,
        const float* __restrict__ vals,
        int* __restrict__ gcur,
        int2* __restrict__ rec) {
    __shared__ int  lcnt[NBUCKET];
    __shared__ int  lbase[NBUCKET];
    __shared__ int  loff[NBUCKET];
    __shared__ int  lcur[NBUCKET];
    __shared__ int  scan[NBUCKET];
    __shared__ int2 sRec[BIN_EDGES];

    const int tid = threadIdx.x;
    if (tid < NBUCKET) lcnt[tid] = 0;
    __syncthreads();

    const size_t e0 = (size_t)blockIdx.x * BIN_EDGES;

    for (int k = tid; k < BIN_EDGES; k += BIN_THREADS) {
        size_t e = e0 + k;
        if (e < N_EDGES)
            atomicAdd(&lcnt[rows[e] / BROWS], 1);
    }
    __syncthreads();

    if (tid < NBUCKET) {
        lbase[tid] = atomicAdd(&gcur[tid], lcnt[tid]);
        scan[tid]  = lcnt[tid];
    }
    __syncthreads();
    for (int off = 1; off < NBUCKET; off <<= 1) {
        int tv = (tid < NBUCKET && tid >= off) ? scan[tid - off] : 0;
        __syncthreads();
        if (tid < NBUCKET) scan[tid] += tv;
        __syncthreads();
    }
    if (tid < NBUCKET) {
        loff[tid] = scan[tid] - lcnt[tid];
        lcur[tid] = loff[tid];
    }
    __syncthreads();

    for (int k = tid; k < BIN_EDGES; k += BIN_THREADS) {
        size_t e = e0 + k;
        if (e < N_EDGES) {
            int r  = rows[e];
            int b  = r / BROWS;
            int rl = r - b * BROWS;
            int slot = atomicAdd(&lcur[b], 1);
            sRec[slot] = make_int2((rl << 18) | cols[e], __float_as_int(vals[e]));
        }
    }
    __syncthreads();

    int wv = tid >> 6, ln = tid & 63;
    for (int b = wv; b < NBUCKET; b += (BIN_THREADS / 64)) {
        int n = lcnt[b], src = loff[b], dst = lbase[b];
        for (int k = ln; k < n; k += 64)
            rec[(size_t)dst + k] = sRec[src + k];
    }
}

// ---------------------------------------------------------------------------
// csr: one block per bucket; LDS hist+scan -> row_start/row_cnt; LDS-cursor
// scatter into the bucket's pair slice. Row starts rounded up to EVEN so
// spmm's int4 pair loads are 16B-aligned.
// ---------------------------------------------------------------------------
__global__ void __launch_bounds__(256) csr_kernel(
        const int2* __restrict__ rec,
        const int* __restrict__ gcur,
        int* __restrict__ row_start,
        int* __restrict__ row_cnt,
        int2* __restrict__ pair) {
    __shared__ int hist[BROWS + 2];
    __shared__ int excl[768];
    __shared__ int part[256];

    const int b    = blockIdx.x;
    const int base = b * BUCKET_CAP;
    const int n    = gcur[b] - base;
    const int lo   = b * BROWS;
    const int t    = threadIdx.x;

    for (int j = t; j < BROWS; j += 256) hist[j] = 0;
    __syncthreads();

    for (int i = t; i < n; i += 256)
        atomicAdd(&hist[rec[base + i].x >> 18], 1);
    __syncthreads();

    // exclusive scan of even-rounded counts -> even row starts
    int vloc[3];
    int s0 = 0;
    #pragma unroll
    for (int k = 0; k < 3; ++k) {
        int idx = t * 3 + k;
        int v = (idx < BROWS) ? ((hist[idx] + 1) & ~1) : 0;
        vloc[k] = s0;
        s0 += v;
    }
    part[t] = s0;
    __syncthreads();
    for (int off = 1; off < 256; off <<= 1) {
        int tv = (t >= off) ? part[t - off] : 0;
        __syncthreads();
        part[t] += tv;
        __syncthreads();
    }
    int pbase = part[t] - s0;
    #pragma unroll
    for (int k = 0; k < 3; ++k) {
        int idx = t * 3 + k;
        if (idx < BROWS) excl[idx] = pbase + vloc[k];
    }
    __syncthreads();

    for (int j = t; j < BROWS; j += 256) {
        row_start[lo + j] = base + excl[j];
        row_cnt[lo + j]   = hist[j];
    }
    __syncthreads();

    for (int i = t; i < n; i += 256) {
        int2 p = rec[base + i];
        int rl = p.x >> 18;
        int slot = atomicAdd(&excl[rl], 1);
        pair[(size_t)base + slot] = make_int2(p.x & 0x3FFFF, p.y);
    }
}

// ---------------------------------------------------------------------------
// gather core: wave per row; lane = g*16+q. Unroll 32: 4x int4 pair loads
// (16B-aligned: row starts even) + 8 independent 128B gathers in flight.
// Returns reduced row float4 (valid lanes 0..15).
// ---------------------------------------------------------------------------
__device__ __forceinline__ float4 gather_row(int s, int e, int g, int q,
                                             const int2* __restrict__ pair,
                                             const uint2* __restrict__ hb) {
    float4 av = make_float4(0.f, 0.f, 0.f, 0.f);
    int i = s;
    for (; i + 32 <= e; i += 32) {
        int4 pp0 = *(const int4*)(pair + i      + 2*g);
        int4 pp1 = *(const int4*)(pair + i +  8 + 2*g);
        int4 pp2 = *(const int4*)(pair + i + 16 + 2*g);
        int4 pp3 = *(const int4*)(pair + i + 24 + 2*g);
        uint2 u0 = hb[(size_t)pp0.x * 16 + q];
        uint2 u1 = hb[(size_t)pp0.z * 16 + q];
        uint2 u2 = hb[(size_t)pp1.x * 16 + q];
        uint2 u3 = hb[(size_t)pp1.z * 16 + q];
        uint2 u4 = hb[(size_t)pp2.x * 16 + q];
        uint2 u5 = hb[(size_t)pp2.z * 16 + q];
        uint2 u6 = hb[(size_t)pp3.x * 16 + q];
        uint2 u7 = hb[(size_t)pp3.z * 16 + q];
        fma4v(__int_as_float(pp0.y), bf2f4(u0), av);
        fma4v(__int_as_float(pp0.w), bf2f4(u1), av);
        fma4v(__int_as_float(pp1.y), bf2f4(u2), av);
        fma4v(__int_as_float(pp1.w), bf2f4(u3), av);
        fma4v(__int_as_float(pp2.y), bf2f4(u4), av);
        fma4v(__int_as_float(pp2.w), bf2f4(u5), av);
        fma4v(__int_as_float(pp3.y), bf2f4(u6), av);
        fma4v(__int_as_float(pp3.w), bf2f4(u7), av);
    }
    if (i + 16 <= e) {
        int4 pp0 = *(const int4*)(pair + i     + 2*g);
        int4 pp1 = *(const int4*)(pair + i + 8 + 2*g);
        uint2 u0 = hb[(size_t)pp0.x * 16 + q];
        uint2 u1 = hb[(size_t)pp0.z * 16 + q];
        uint2 u2 = hb[(size_t)pp1.x * 16 + q];
        uint2 u3 = hb[(size_t)pp1.z * 16 + q];
        fma4v(__int_as_float(pp0.y), bf2f4(u0), av);
        fma4v(__int_as_float(pp0.w), bf2f4(u1), av);
        fma4v(__int_as_float(pp1.y), bf2f4(u2), av);
        fma4v(__int_as_float(pp1.w), bf2f4(u3), av);
        i += 16;
    }
    if (i + 8 <= e) {
        int4 pp0 = *(const int4*)(pair + i + 2*g);
        uint2 u0 = hb[(size_t)pp0.x * 16 + q];
        uint2 u1 = hb[(size_t)pp0.z * 16 + q];
        fma4v(__int_as_float(pp0.y), bf2f4(u0), av);
        fma4v(__int_as_float(pp0.w), bf2f4(u1), av);
        i += 8;
    }
    if (i + 4 <= e) {
        int2 p0 = pair[i + g];
        uint2 u0 = hb[(size_t)p0.x * 16 + q];
        fma4v(__int_as_float(p0.y), bf2f4(u0), av);
        i += 4;
    }
    if (i < e) {
        int idx = i + g;
        int2 pD = pair[(idx < e) ? idx : (e - 1)];
        float vD = (idx < e) ? __int_as_float(pD.y) : 0.0f;
        uint2 uD = hb[(size_t)pD.x * 16 + q];
        fma4v(vD, bf2f4(uD), av);
    }
    av.x += __shfl_xor(av.x, 32, 64);
    av.y += __shfl_xor(av.y, 32, 64);
    av.z += __shfl_xor(av.z, 32, 64);
    av.w += __shfl_xor(av.w, 32, 64);
    av.x += __shfl_xor(av.x, 16, 64);
    av.y += __shfl_xor(av.y, 16, 64);
    av.z += __shfl_xor(av.z, 16, 64);
    av.w += __shfl_xor(av.w, 16, 64);
    return av;
}

// ---------------------------------------------------------------------------
// spmm layer: hn = bf16(A * hb)
// ---------------------------------------------------------------------------
__global__ void spmm_kernel(const int* __restrict__ row_start,
                            const int* __restrict__ row_cnt,
                            const int2* __restrict__ pair,
                            const uint2* __restrict__ hb,
                            uint2* __restrict__ hn) {
    int wid  = (int)(((size_t)blockIdx.x * blockDim.x + threadIdx.x) >> 6);
    int lane = threadIdx.x & 63;
    int g = lane >> 4, q = lane & 15;
    if (wid >= N_NODES) return;
    int s = row_start[wid];
    int e = s + row_cnt[wid];

    float4 av = gather_row(s, e, g, q, pair, hb);

    if (lane < 16)
        hn[(size_t)wid * 16 + q] = f42bf(av);
}

// ---------------------------------------------------------------------------
// final: for the 2*N_QUERY (possibly duplicated) queried rows —
// h3 = (A*hB)[row]; fin[row] = 0.25*(ego_fp32 + hA + hB + h3).
// Duplicate rows write identical values (benign race).
// ---------------------------------------------------------------------------
__global__ void final_kernel(const int* __restrict__ row_start,
                             const int* __restrict__ row_cnt,
                             const int2* __restrict__ pair,
                             const uint2* __restrict__ hB,
                             const uint2* __restrict__ hA,
                             const float4* __restrict__ ue4,
                             const float4* __restrict__ ie4,
                             float4* __restrict__ fin4,
                             const int* __restrict__ users,
                             const int* __restrict__ items) {
    int wid  = (int)(((size_t)blockIdx.x * blockDim.x + threadIdx.x) >> 6);
    int lane = threadIdx.x & 63;
    int g = lane >> 4, q = lane & 15;
    if (wid >= 2 * N_QUERY) return;
    int row = (wid < N_QUERY) ? users[wid] : (NUM_USERS + items[wid - N_QUERY]);
    int s = row_start[row];
    int e = s + row_cnt[row];

    float4 av = gather_row(s, e, g, q, pair, hB);

    if (lane < 16) {
        size_t o = (size_t)row * 16 + q;
        float4 ego = (row < NUM_USERS)
                   ? ue4[(size_t)row * 16 + q]
                   : ie4[(size_t)(row - NUM_USERS) * 16 + q];
        float4 a1 = bf2f4(hA[o]);
        float4 a2 = bf2f4(hB[o]);
        float4 f;
        f.x = 0.25f * (ego.x + a1.x + a2.x + av.x);
        f.y = 0.25f * (ego.y + a1.y + a2.y + av.y);
        f.z = 0.25f * (ego.z + a1.z + a2.z + av.z);
        f.w = 0.25f * (ego.w + a1.w + a2.w + av.w);
        fin4[o] = f;
    }
}

// ---------------------------------------------------------------------------
// out[q] = dot(fin[users[q]], fin[NUM_USERS + items[q]])
// ---------------------------------------------------------------------------
__global__ void dot_kernel(const int* __restrict__ users,
                           const int* __restrict__ items,
                           const float* __restrict__ fin,
                           float* __restrict__ out) {
    int lane = threadIdx.x & 63;
    int wave = threadIdx.x >> 6;
    int q    = blockIdx.x * (blockDim.x >> 6) + wave;
    if (q >= N_QUERY) return;

    float a = fin[(size_t)users[q] * EMBED_DIM + lane];
    float b = fin[((size_t)NUM_USERS + items[q]) * EMBED_DIM + lane];
    float p = a * b;

    #pragma unroll
    for (int off = 32; off >= 1; off >>= 1)
        p += __shfl_xor(p, off, 64);

    if (lane == 0)
        out[q] = p;
}

// ---------------------------------------------------------------------------
extern "C" void kernel_launch(void* const* d_in, const int* in_sizes, int n_in,
                              void* d_out, int out_size, void* d_ws, size_t ws_size,
                              hipStream_t stream) {
    const int*   users = (const int*)  d_in[0];
    const int*   items = (const int*)  d_in[1];
    const float* ue    = (const float*)d_in[2];
    const float* ie    = (const float*)d_in[3];
    const int*   rows  = (const int*)  d_in[4];
    const int*   cols  = (const int*)  d_in[5];
    const float* vals  = (const float*)d_in[6];
    float*       out   = (float*)d_out;

    const size_t REC_N = (size_t)NBUCKET * BUCKET_CAP;   // 5,242,880

    // workspace layout (~140 MB):
    //   fin fp32 | ego_bf | hA_bf | hB_bf | pair | ints
    //   rec aliases [ego_bf ..) — dead before those are written
    float* fin    = (float*)d_ws;                        // 9.6M f  (38.4 MB)
    uint2* ego_bf = (uint2*)(fin + NODE_FLOATS);         // 2.4M u2 (19.2 MB)
    uint2* hA_bf  = ego_bf + NODE_FLOAT4;                // 2.4M u2 (19.2 MB)
    uint2* hB_bf  = hA_bf + NODE_FLOAT4;                 // 2.4M u2 (19.2 MB)
    int2*  rec    = (int2*)ego_bf;                       // 41.9 MB (aliased)
    int2*  pair   = (int2*)(hB_bf + NODE_FLOAT4);        // 41.9 MB

    int* row_start = (int*)(pair + REC_N);               // 150,016 i
    int* row_cnt   = row_start + 150016;                 // 150,016 i
    int* gcur      = row_cnt + 150016;                   // 256 i

    int vec_blocks = (int)((NODE_FLOAT4 + 255) / 256);

    init_gcur_kernel<<<1, 256, 0, stream>>>(gcur);
    bin_kernel<<<BIN_BLOCKS, BIN_THREADS, 0, stream>>>(rows, cols, vals, gcur, rec);
    csr_kernel<<<NBUCKET, 256, 0, stream>>>(rec, gcur, row_start, row_cnt, pair);

    // rec dead -> build bf16 ego in its place
    ego_bf_kernel<<<vec_blocks, 256, 0, stream>>>(
        (const float4*)ue, (const float4*)ie, ego_bf);

    int spmm_blocks = (N_NODES * 64 + 255) / 256;
    spmm_kernel<<<spmm_blocks, 256, 0, stream>>>(row_start, row_cnt, pair, ego_bf, hA_bf);
    spmm_kernel<<<spmm_blocks, 256, 0, stream>>>(row_start, row_cnt, pair, hA_bf, hB_bf);

    int q_blocks = (2 * N_QUERY * 64 + 255) / 256;       // 8192
    final_kernel<<<q_blocks, 256, 0, stream>>>(row_start, row_cnt, pair,
        hB_bf, hA_bf, (const float4*)ue, (const float4*)ie, (float4*)fin,
        users, items);

    dot_kernel<<<(N_QUERY + 3) / 4, 256, 0, stream>>>(users, items, fin, out);
}

// Round 12
// 333.628 us; speedup vs baseline: 36.5335x; 1.0060x over previous
//
#include <hip/hip_runtime.h>

#define NUM_USERS 100000
#define NUM_ITEMS 50000
#define EMBED_DIM 64
#define N_NODES   (NUM_USERS + NUM_ITEMS)      // 150000
#define N_EDGES   4800000
#define N_QUERY   16384

#define NODE_FLOATS ((size_t)N_NODES * EMBED_DIM)   // 9,600,000
#define NODE_FLOAT4 (NODE_FLOATS / 4)                // 2,400,000

#define NBUCKET    256
#define BROWS      586                               // 256*586 = 150016 rows
#define BUCKET_CAP 20480
#define BIN_EDGES  8192
#define BIN_THREADS 512
#define BIN_BLOCKS ((N_EDGES + BIN_EDGES - 1) / BIN_EDGES)  // 586
#define EGO_SLICE  (NODE_FLOAT4 / NBUCKET)            // 9375 float4 per csr block

// ---------------------------------------------------------------------------
// bf16 pack/unpack helpers (RNE)
// ---------------------------------------------------------------------------
__device__ __forceinline__ float4 bf2f4(uint2 u) {
    float4 f;
    f.x = __uint_as_float(u.x << 16);
    f.y = __uint_as_float(u.x & 0xFFFF0000u);
    f.z = __uint_as_float(u.y << 16);
    f.w = __uint_as_float(u.y & 0xFFFF0000u);
    return f;
}
__device__ __forceinline__ unsigned rne_bf(float f) {
    unsigned b = __float_as_uint(f);
    return (b + 0x7FFFu + ((b >> 16) & 1u)) >> 16;
}
__device__ __forceinline__ uint2 f42bf(float4 f) {
    uint2 u;
    u.x = rne_bf(f.x) | (rne_bf(f.y) << 16);
    u.y = rne_bf(f.z) | (rne_bf(f.w) << 16);
    return u;
}
__device__ __forceinline__ void fma4v(float v, float4 xv, float4& av) {
    av.x = fmaf(v, xv.x, av.x);
    av.y = fmaf(v, xv.y, av.y);
    av.z = fmaf(v, xv.z, av.z);
    av.w = fmaf(v, xv.w, av.w);
}

// ---------------------------------------------------------------------------
// bin: single edge read -> 256 row-range buckets (LDS-staged). Dense
// copy-out via per-slot bucket ids. gcur starts zeroed; bucket base offset
// added in-kernel.
// ---------------------------------------------------------------------------
__global__ void __launch_bounds__(BIN_THREADS) bin_kernel(
        const int* __restrict__ rows,
        const int* __restrict__ cols,
        const float* __restrict__ vals,
        int* __restrict__ gcur,
        int2* __restrict__ rec) {
    __shared__ int  lcnt[NBUCKET];
    __shared__ int  lbase[NBUCKET];
    __shared__ int  loff[NBUCKET];
    __shared__ int  lcur[NBUCKET];
    __shared__ int  scan[NBUCKET];
    __shared__ int2 sRec[BIN_EDGES];
    __shared__ unsigned char sBkt[BIN_EDGES];

    const int tid = threadIdx.x;
    if (tid < NBUCKET) lcnt[tid] = 0;
    __syncthreads();

    const size_t e0 = (size_t)blockIdx.x * BIN_EDGES;
    const int nrec = (int)(((size_t)N_EDGES - e0) < BIN_EDGES ? (N_EDGES - e0)
                                                              : BIN_EDGES);

    // pass 1: bucket counts
    for (int k = tid; k < nrec; k += BIN_THREADS)
        atomicAdd(&lcnt[rows[e0 + k] / BROWS], 1);
    __syncthreads();

    // claim global ranges (gcur zero-based; add bucket region base)
    if (tid < NBUCKET) {
        lbase[tid] = tid * BUCKET_CAP + atomicAdd(&gcur[tid], lcnt[tid]);
        scan[tid]  = lcnt[tid];
    }
    __syncthreads();
    for (int off = 1; off < NBUCKET; off <<= 1) {
        int tv = (tid < NBUCKET && tid >= off) ? scan[tid - off] : 0;
        __syncthreads();
        if (tid < NBUCKET) scan[tid] += tv;
        __syncthreads();
    }
    if (tid < NBUCKET) {
        loff[tid] = scan[tid] - lcnt[tid];
        lcur[tid] = loff[tid];
    }
    __syncthreads();

    // pass 2: stage records bucket-sorted in LDS, record bucket per slot
    for (int k = tid; k < nrec; k += BIN_THREADS) {
        int r  = rows[e0 + k];
        int b  = r / BROWS;
        int rl = r - b * BROWS;
        int slot = atomicAdd(&lcur[b], 1);
        sRec[slot] = make_int2((rl << 18) | cols[e0 + k],
                               __float_as_int(vals[e0 + k]));
        sBkt[slot] = (unsigned char)b;
    }
    __syncthreads();

    // dense coalesced copy-out
    for (int k = tid; k < nrec; k += BIN_THREADS) {
        int bk = sBkt[k];
        rec[(size_t)lbase[bk] + (k - loff[bk])] = sRec[k];
    }
}

// ---------------------------------------------------------------------------
// csr: one block per bucket; LDS hist+scan -> row_start/row_cnt (even-aligned
// starts); LDS-cursor scatter into the bucket's pair slice. Also converts a
// slice of ego to bf16 (fused, independent work).
// ---------------------------------------------------------------------------
__global__ void __launch_bounds__(256) csr_kernel(
        const int2* __restrict__ rec,
        const int* __restrict__ gcur,
        int* __restrict__ row_start,
        int* __restrict__ row_cnt,
        int2* __restrict__ pair,
        const float4* __restrict__ ue4,
        const float4* __restrict__ ie4,
        uint2* __restrict__ ego) {
    __shared__ int hist[BROWS + 2];
    __shared__ int excl[768];
    __shared__ int part[256];

    const int b    = blockIdx.x;
    const int base = b * BUCKET_CAP;
    const int n    = gcur[b];
    const int lo   = b * BROWS;
    const int t    = threadIdx.x;

    // fused ego bf16 conversion (independent; overlaps hist latency)
    {
        const size_t user_f4 = (size_t)NUM_USERS * EMBED_DIM / 4;
        size_t s0 = (size_t)b * EGO_SLICE;
        for (int j = t; j < EGO_SLICE; j += 256) {
            size_t idx = s0 + j;
            float4 v = (idx < user_f4) ? ue4[idx] : ie4[idx - user_f4];
            ego[idx] = f42bf(v);
        }
    }

    for (int j = t; j < BROWS; j += 256) hist[j] = 0;
    __syncthreads();

    for (int i = t; i < n; i += 256)
        atomicAdd(&hist[rec[base + i].x >> 18], 1);
    __syncthreads();

    // exclusive scan of even-rounded counts -> even row starts
    int vloc[3];
    int s0 = 0;
    #pragma unroll
    for (int k = 0; k < 3; ++k) {
        int idx = t * 3 + k;
        int v = (idx < BROWS) ? ((hist[idx] + 1) & ~1) : 0;
        vloc[k] = s0;
        s0 += v;
    }
    part[t] = s0;
    __syncthreads();
    for (int off = 1; off < 256; off <<= 1) {
        int tv = (t >= off) ? part[t - off] : 0;
        __syncthreads();
        part[t] += tv;
        __syncthreads();
    }
    int pbase = part[t] - s0;
    #pragma unroll
    for (int k = 0; k < 3; ++k) {
        int idx = t * 3 + k;
        if (idx < BROWS) excl[idx] = pbase + vloc[k];
    }
    __syncthreads();

    for (int j = t; j < BROWS; j += 256) {
        row_start[lo + j] = base + excl[j];
        row_cnt[lo + j]   = hist[j];
    }
    __syncthreads();

    for (int i = t; i < n; i += 256) {
        int2 p = rec[base + i];
        int rl = p.x >> 18;
        int slot = atomicAdd(&excl[rl], 1);
        pair[(size_t)base + slot] = make_int2(p.x & 0x3FFFF, p.y);
    }
}

// ---------------------------------------------------------------------------
// gather core: wave per row; lane = g*16+q. Unroll 32: 4x int4 pair loads
// (16B-aligned: row starts even) + 8 independent 128B gathers in flight.
// Returns reduced row float4 (valid lanes 0..15).
// ---------------------------------------------------------------------------
__device__ __forceinline__ float4 gather_row(int s, int e, int g, int q,
                                             const int2* __restrict__ pair,
                                             const uint2* __restrict__ hb) {
    float4 av = make_float4(0.f, 0.f, 0.f, 0.f);
    int i = s;
    for (; i + 32 <= e; i += 32) {
        int4 pp0 = *(const int4*)(pair + i      + 2*g);
        int4 pp1 = *(const int4*)(pair + i +  8 + 2*g);
        int4 pp2 = *(const int4*)(pair + i + 16 + 2*g);
        int4 pp3 = *(const int4*)(pair + i + 24 + 2*g);
        uint2 u0 = hb[(size_t)pp0.x * 16 + q];
        uint2 u1 = hb[(size_t)pp0.z * 16 + q];
        uint2 u2 = hb[(size_t)pp1.x * 16 + q];
        uint2 u3 = hb[(size_t)pp1.z * 16 + q];
        uint2 u4 = hb[(size_t)pp2.x * 16 + q];
        uint2 u5 = hb[(size_t)pp2.z * 16 + q];
        uint2 u6 = hb[(size_t)pp3.x * 16 + q];
        uint2 u7 = hb[(size_t)pp3.z * 16 + q];
        fma4v(__int_as_float(pp0.y), bf2f4(u0), av);
        fma4v(__int_as_float(pp0.w), bf2f4(u1), av);
        fma4v(__int_as_float(pp1.y), bf2f4(u2), av);
        fma4v(__int_as_float(pp1.w), bf2f4(u3), av);
        fma4v(__int_as_float(pp2.y), bf2f4(u4), av);
        fma4v(__int_as_float(pp2.w), bf2f4(u5), av);
        fma4v(__int_as_float(pp3.y), bf2f4(u6), av);
        fma4v(__int_as_float(pp3.w), bf2f4(u7), av);
    }
    if (i + 16 <= e) {
        int4 pp0 = *(const int4*)(pair + i     + 2*g);
        int4 pp1 = *(const int4*)(pair + i + 8 + 2*g);
        uint2 u0 = hb[(size_t)pp0.x * 16 + q];
        uint2 u1 = hb[(size_t)pp0.z * 16 + q];
        uint2 u2 = hb[(size_t)pp1.x * 16 + q];
        uint2 u3 = hb[(size_t)pp1.z * 16 + q];
        fma4v(__int_as_float(pp0.y), bf2f4(u0), av);
        fma4v(__int_as_float(pp0.w), bf2f4(u1), av);
        fma4v(__int_as_float(pp1.y), bf2f4(u2), av);
        fma4v(__int_as_float(pp1.w), bf2f4(u3), av);
        i += 16;
    }
    if (i + 8 <= e) {
        int4 pp0 = *(const int4*)(pair + i + 2*g);
        uint2 u0 = hb[(size_t)pp0.x * 16 + q];
        uint2 u1 = hb[(size_t)pp0.z * 16 + q];
        fma4v(__int_as_float(pp0.y), bf2f4(u0), av);
        fma4v(__int_as_float(pp0.w), bf2f4(u1), av);
        i += 8;
    }
    if (i + 4 <= e) {
        int2 p0 = pair[i + g];
        uint2 u0 = hb[(size_t)p0.x * 16 + q];
        fma4v(__int_as_float(p0.y), bf2f4(u0), av);
        i += 4;
    }
    if (i < e) {
        int idx = i + g;
        int2 pD = pair[(idx < e) ? idx : (e - 1)];
        float vD = (idx < e) ? __int_as_float(pD.y) : 0.0f;
        uint2 uD = hb[(size_t)pD.x * 16 + q];
        fma4v(vD, bf2f4(uD), av);
    }
    av.x += __shfl_xor(av.x, 32, 64);
    av.y += __shfl_xor(av.y, 32, 64);
    av.z += __shfl_xor(av.z, 32, 64);
    av.w += __shfl_xor(av.w, 32, 64);
    av.x += __shfl_xor(av.x, 16, 64);
    av.y += __shfl_xor(av.y, 16, 64);
    av.z += __shfl_xor(av.z, 16, 64);
    av.w += __shfl_xor(av.w, 16, 64);
    return av;
}

// ---------------------------------------------------------------------------
// spmm layer: hn = bf16(A * hb)
// ---------------------------------------------------------------------------
__global__ void spmm_kernel(const int* __restrict__ row_start,
                            const int* __restrict__ row_cnt,
                            const int2* __restrict__ pair,
                            const uint2* __restrict__ hb,
                            uint2* __restrict__ hn) {
    int wid  = (int)(((size_t)blockIdx.x * blockDim.x + threadIdx.x) >> 6);
    int lane = threadIdx.x & 63;
    int g = lane >> 4, q = lane & 15;
    if (wid >= N_NODES) return;
    int s = row_start[wid];
    int e = s + row_cnt[wid];

    float4 av = gather_row(s, e, g, q, pair, hb);

    if (lane < 16)
        hn[(size_t)wid * 16 + q] = f42bf(av);
}

// ---------------------------------------------------------------------------
// fused final+dot: one wave per query. Compute fin_u and fin_i in-register
// (fin = 0.25*(ego + hA + hB + A*hB)), dot them, write out[query].
// ---------------------------------------------------------------------------
__device__ __forceinline__ float4 fin_row(int row, int g, int q, int lane,
                                          const int* __restrict__ row_start,
                                          const int* __restrict__ row_cnt,
                                          const int2* __restrict__ pair,
                                          const uint2* __restrict__ hA,
                                          const uint2* __restrict__ hB,
                                          const float4* __restrict__ ue4,
                                          const float4* __restrict__ ie4) {
    int s = row_start[row];
    int e = s + row_cnt[row];
    float4 av = gather_row(s, e, g, q, pair, hB);
    float4 f = make_float4(0.f, 0.f, 0.f, 0.f);
    if (lane < 16) {
        size_t o = (size_t)row * 16 + q;
        float4 ego = (row < NUM_USERS)
                   ? ue4[(size_t)row * 16 + q]
                   : ie4[(size_t)(row - NUM_USERS) * 16 + q];
        float4 a1 = bf2f4(hA[o]);
        float4 a2 = bf2f4(hB[o]);
        f.x = 0.25f * (ego.x + a1.x + a2.x + av.x);
        f.y = 0.25f * (ego.y + a1.y + a2.y + av.y);
        f.z = 0.25f * (ego.z + a1.z + a2.z + av.z);
        f.w = 0.25f * (ego.w + a1.w + a2.w + av.w);
    }
    return f;
}

__global__ void score_kernel(const int* __restrict__ row_start,
                             const int* __restrict__ row_cnt,
                             const int2* __restrict__ pair,
                             const uint2* __restrict__ hA,
                             const uint2* __restrict__ hB,
                             const float4* __restrict__ ue4,
                             const float4* __restrict__ ie4,
                             const int* __restrict__ users,
                             const int* __restrict__ items,
                             float* __restrict__ out) {
    int qid  = (int)(((size_t)blockIdx.x * blockDim.x + threadIdx.x) >> 6);
    int lane = threadIdx.x & 63;
    int g = lane >> 4, q = lane & 15;
    if (qid >= N_QUERY) return;

    int urow = users[qid];
    int irow = NUM_USERS + items[qid];

    float4 fu = fin_row(urow, g, q, lane, row_start, row_cnt, pair, hA, hB, ue4, ie4);
    float4 fi = fin_row(irow, g, q, lane, row_start, row_cnt, pair, hA, hB, ue4, ie4);

    float p = fu.x * fi.x + fu.y * fi.y + fu.z * fi.z + fu.w * fi.w;
    // reduce over lanes 0..15 (lanes 16+ contribute 0)
    p += __shfl_xor(p, 8, 64);
    p += __shfl_xor(p, 4, 64);
    p += __shfl_xor(p, 2, 64);
    p += __shfl_xor(p, 1, 64);

    if (lane == 0)
        out[qid] = p;
}

// ---------------------------------------------------------------------------
extern "C" void kernel_launch(void* const* d_in, const int* in_sizes, int n_in,
                              void* d_out, int out_size, void* d_ws, size_t ws_size,
                              hipStream_t stream) {
    const int*   users = (const int*)  d_in[0];
    const int*   items = (const int*)  d_in[1];
    const float* ue    = (const float*)d_in[2];
    const float* ie    = (const float*)d_in[3];
    const int*   rows  = (const int*)  d_in[4];
    const int*   cols  = (const int*)  d_in[5];
    const float* vals  = (const float*)d_in[6];
    float*       out   = (float*)d_out;

    const size_t REC_N = (size_t)NBUCKET * BUCKET_CAP;   // 5,242,880

    // workspace layout (~144 MB, no aliasing):
    //   ego_bf | hA_bf | hB_bf | rec | pair | ints
    uint2* ego_bf = (uint2*)d_ws;                        // 2.4M u2 (19.2 MB)
    uint2* hA_bf  = ego_bf + NODE_FLOAT4;                // 19.2 MB
    uint2* hB_bf  = hA_bf + NODE_FLOAT4;                 // 19.2 MB
    int2*  rec    = (int2*)(hB_bf + NODE_FLOAT4);        // 41.9 MB
    int2*  pair   = rec + REC_N;                         // 41.9 MB

    int* row_start = (int*)(pair + REC_N);               // 150,016 i
    int* row_cnt   = row_start + 150016;                 // 150,016 i
    int* gcur      = row_cnt + 150016;                   // 256 i

    (void)hipMemsetAsync(gcur, 0, NBUCKET * sizeof(int), stream);

    bin_kernel<<<BIN_BLOCKS, BIN_THREADS, 0, stream>>>(rows, cols, vals, gcur, rec);
    csr_kernel<<<NBUCKET, 256, 0, stream>>>(rec, gcur, row_start, row_cnt, pair,
        (const float4*)ue, (const float4*)ie, ego_bf);

    int spmm_blocks = (N_NODES * 64 + 255) / 256;
    spmm_kernel<<<spmm_blocks, 256, 0, stream>>>(row_start, row_cnt, pair, ego_bf, hA_bf);
    spmm_kernel<<<spmm_blocks, 256, 0, stream>>>(row_start, row_cnt, pair, hA_bf, hB_bf);

    int score_blocks = (N_QUERY * 64 + 255) / 256;       // 4096
    score_kernel<<<score_blocks, 256, 0, stream>>>(row_start, row_cnt, pair,
        hA_bf, hB_bf, (const float4*)ue, (const float4*)ie, users, items, out);
}

// Round 13
// 316.040 us; speedup vs baseline: 38.5666x; 1.0557x over previous
//
#include <hip/hip_runtime.h>

#define NUM_USERS 100000
#define NUM_ITEMS 50000
#define EMBED_DIM 64
#define N_NODES   (NUM_USERS + NUM_ITEMS)      // 150000
#define N_EDGES   4800000
#define N_QUERY   16384

#define NODE_FLOATS ((size_t)N_NODES * EMBED_DIM)   // 9,600,000
#define NODE_FLOAT4 (NODE_FLOATS / 4)                // 2,400,000

#define NBUCKET    256
#define BROWS      586                               // 256*586 = 150016 rows
#define BUCKET_CAP 20480
#define BIN_EDGES  4096
#define BIN_THREADS 512
#define BIN_BLOCKS ((N_EDGES + BIN_EDGES - 1) / BIN_EDGES)  // 1172
#define CSR_THREADS 512
#define EGO_SLICE  (NODE_FLOAT4 / NBUCKET)            // 9375 float4 per csr block

// ---------------------------------------------------------------------------
// bf16 pack/unpack helpers (RNE)
// ---------------------------------------------------------------------------
__device__ __forceinline__ float4 bf2f4(uint2 u) {
    float4 f;
    f.x = __uint_as_float(u.x << 16);
    f.y = __uint_as_float(u.x & 0xFFFF0000u);
    f.z = __uint_as_float(u.y << 16);
    f.w = __uint_as_float(u.y & 0xFFFF0000u);
    return f;
}
__device__ __forceinline__ unsigned rne_bf(float f) {
    unsigned b = __float_as_uint(f);
    return (b + 0x7FFFu + ((b >> 16) & 1u)) >> 16;
}
__device__ __forceinline__ uint2 f42bf(float4 f) {
    uint2 u;
    u.x = rne_bf(f.x) | (rne_bf(f.y) << 16);
    u.y = rne_bf(f.z) | (rne_bf(f.w) << 16);
    return u;
}
__device__ __forceinline__ void fma4v(float v, float4 xv, float4& av) {
    av.x = fmaf(v, xv.x, av.x);
    av.y = fmaf(v, xv.y, av.y);
    av.z = fmaf(v, xv.z, av.z);
    av.w = fmaf(v, xv.w, av.w);
}

// ---------------------------------------------------------------------------
// bin: single edge read -> 256 row-range buckets (LDS-staged). Dense
// copy-out; also emits u16 row-local ids (recRl) for csr's cheap hist.
// 4096 edges/block @ 41 KB LDS -> 3 blocks/CU.
// ---------------------------------------------------------------------------
__global__ void __launch_bounds__(BIN_THREADS) bin_kernel(
        const int* __restrict__ rows,
        const int* __restrict__ cols,
        const float* __restrict__ vals,
        int* __restrict__ gcur,
        int2* __restrict__ rec,
        unsigned short* __restrict__ recRl) {
    __shared__ int  lcnt[NBUCKET];
    __shared__ int  lbase[NBUCKET];
    __shared__ int  loff[NBUCKET];
    __shared__ int  lcur[NBUCKET];
    __shared__ int  scan[NBUCKET];
    __shared__ int2 sRec[BIN_EDGES];
    __shared__ unsigned char sBkt[BIN_EDGES];

    const int tid = threadIdx.x;
    if (tid < NBUCKET) lcnt[tid] = 0;
    __syncthreads();

    const size_t e0 = (size_t)blockIdx.x * BIN_EDGES;
    const int nrec = (int)(((size_t)N_EDGES - e0) < BIN_EDGES ? (N_EDGES - e0)
                                                              : BIN_EDGES);

    // pass 1: bucket counts
    for (int k = tid; k < nrec; k += BIN_THREADS)
        atomicAdd(&lcnt[rows[e0 + k] / BROWS], 1);
    __syncthreads();

    // claim global ranges (gcur zero-based; add bucket region base)
    if (tid < NBUCKET) {
        lbase[tid] = tid * BUCKET_CAP + atomicAdd(&gcur[tid], lcnt[tid]);
        scan[tid]  = lcnt[tid];
    }
    __syncthreads();
    for (int off = 1; off < NBUCKET; off <<= 1) {
        int tv = (tid < NBUCKET && tid >= off) ? scan[tid - off] : 0;
        __syncthreads();
        if (tid < NBUCKET) scan[tid] += tv;
        __syncthreads();
    }
    if (tid < NBUCKET) {
        loff[tid] = scan[tid] - lcnt[tid];
        lcur[tid] = loff[tid];
    }
    __syncthreads();

    // pass 2: stage records bucket-sorted in LDS, record bucket per slot
    for (int k = tid; k < nrec; k += BIN_THREADS) {
        int r  = rows[e0 + k];
        int b  = r / BROWS;
        int rl = r - b * BROWS;
        int slot = atomicAdd(&lcur[b], 1);
        sRec[slot] = make_int2((rl << 18) | cols[e0 + k],
                               __float_as_int(vals[e0 + k]));
        sBkt[slot] = (unsigned char)b;
    }
    __syncthreads();

    // dense coalesced copy-out (+ u16 row-local id stream)
    for (int k = tid; k < nrec; k += BIN_THREADS) {
        int bk = sBkt[k];
        int2 r = sRec[k];
        size_t d = (size_t)lbase[bk] + (k - loff[bk]);
        rec[d]   = r;
        recRl[d] = (unsigned short)((unsigned)r.x >> 18);
    }
}

// ---------------------------------------------------------------------------
// csr: one block per bucket, 512 threads (8 waves/CU). Hist reads the u16
// recRl stream; scan (even-aligned starts); LDS-cursor scatter into the
// bucket's pair slice. Fused ego bf16 conversion.
// ---------------------------------------------------------------------------
__global__ void __launch_bounds__(CSR_THREADS) csr_kernel(
        const int2* __restrict__ rec,
        const unsigned short* __restrict__ recRl,
        const int* __restrict__ gcur,
        int* __restrict__ row_start,
        int* __restrict__ row_cnt,
        int2* __restrict__ pair,
        const float4* __restrict__ ue4,
        const float4* __restrict__ ie4,
        uint2* __restrict__ ego) {
    __shared__ int hist[BROWS + 2];
    __shared__ int excl[1024];
    __shared__ int part[CSR_THREADS];

    const int b    = blockIdx.x;
    const int base = b * BUCKET_CAP;
    const int n    = gcur[b];
    const int lo   = b * BROWS;
    const int t    = threadIdx.x;

    // fused ego bf16 conversion (independent; overlaps hist latency)
    {
        const size_t user_f4 = (size_t)NUM_USERS * EMBED_DIM / 4;
        size_t s0 = (size_t)b * EGO_SLICE;
        for (int j = t; j < EGO_SLICE; j += CSR_THREADS) {
            size_t idx = s0 + j;
            float4 v = (idx < user_f4) ? ue4[idx] : ie4[idx - user_f4];
            ego[idx] = f42bf(v);
        }
    }

    for (int j = t; j < BROWS; j += CSR_THREADS) hist[j] = 0;
    __syncthreads();

    // pass 1: histogram from the compact u16 stream
    for (int i = t; i < n; i += CSR_THREADS)
        atomicAdd(&hist[recRl[base + i]], 1);
    __syncthreads();

    // exclusive scan of even-rounded counts -> even row starts (2/thread)
    int vloc[2];
    int s0 = 0;
    #pragma unroll
    for (int k = 0; k < 2; ++k) {
        int idx = t * 2 + k;
        int v = (idx < BROWS) ? ((hist[idx] + 1) & ~1) : 0;
        vloc[k] = s0;
        s0 += v;
    }
    part[t] = s0;
    __syncthreads();
    for (int off = 1; off < CSR_THREADS; off <<= 1) {
        int tv = (t >= off) ? part[t - off] : 0;
        __syncthreads();
        part[t] += tv;
        __syncthreads();
    }
    int pbase = part[t] - s0;
    #pragma unroll
    for (int k = 0; k < 2; ++k) {
        int idx = t * 2 + k;
        if (idx < BROWS) excl[idx] = pbase + vloc[k];
    }
    __syncthreads();

    for (int j = t; j < BROWS; j += CSR_THREADS) {
        row_start[lo + j] = base + excl[j];
        row_cnt[lo + j]   = hist[j];
    }
    __syncthreads();

    // pass 2: scatter; excl doubles as cursors
    for (int i = t; i < n; i += CSR_THREADS) {
        int2 p = rec[base + i];
        int rl = (unsigned)p.x >> 18;
        int slot = atomicAdd(&excl[rl], 1);
        pair[(size_t)base + slot] = make_int2(p.x & 0x3FFFF, p.y);
    }
}

// ---------------------------------------------------------------------------
// gather core: wave per row; lane = g*16+q. Unroll 32: 4x int4 pair loads
// (16B-aligned: row starts even) + 8 independent 128B gathers in flight.
// Returns reduced row float4 (valid lanes 0..15).
// ---------------------------------------------------------------------------
__device__ __forceinline__ float4 gather_row(int s, int e, int g, int q,
                                             const int2* __restrict__ pair,
                                             const uint2* __restrict__ hb) {
    float4 av = make_float4(0.f, 0.f, 0.f, 0.f);
    int i = s;
    for (; i + 32 <= e; i += 32) {
        int4 pp0 = *(const int4*)(pair + i      + 2*g);
        int4 pp1 = *(const int4*)(pair + i +  8 + 2*g);
        int4 pp2 = *(const int4*)(pair + i + 16 + 2*g);
        int4 pp3 = *(const int4*)(pair + i + 24 + 2*g);
        uint2 u0 = hb[(size_t)pp0.x * 16 + q];
        uint2 u1 = hb[(size_t)pp0.z * 16 + q];
        uint2 u2 = hb[(size_t)pp1.x * 16 + q];
        uint2 u3 = hb[(size_t)pp1.z * 16 + q];
        uint2 u4 = hb[(size_t)pp2.x * 16 + q];
        uint2 u5 = hb[(size_t)pp2.z * 16 + q];
        uint2 u6 = hb[(size_t)pp3.x * 16 + q];
        uint2 u7 = hb[(size_t)pp3.z * 16 + q];
        fma4v(__int_as_float(pp0.y), bf2f4(u0), av);
        fma4v(__int_as_float(pp0.w), bf2f4(u1), av);
        fma4v(__int_as_float(pp1.y), bf2f4(u2), av);
        fma4v(__int_as_float(pp1.w), bf2f4(u3), av);
        fma4v(__int_as_float(pp2.y), bf2f4(u4), av);
        fma4v(__int_as_float(pp2.w), bf2f4(u5), av);
        fma4v(__int_as_float(pp3.y), bf2f4(u6), av);
        fma4v(__int_as_float(pp3.w), bf2f4(u7), av);
    }
    if (i + 16 <= e) {
        int4 pp0 = *(const int4*)(pair + i     + 2*g);
        int4 pp1 = *(const int4*)(pair + i + 8 + 2*g);
        uint2 u0 = hb[(size_t)pp0.x * 16 + q];
        uint2 u1 = hb[(size_t)pp0.z * 16 + q];
        uint2 u2 = hb[(size_t)pp1.x * 16 + q];
        uint2 u3 = hb[(size_t)pp1.z * 16 + q];
        fma4v(__int_as_float(pp0.y), bf2f4(u0), av);
        fma4v(__int_as_float(pp0.w), bf2f4(u1), av);
        fma4v(__int_as_float(pp1.y), bf2f4(u2), av);
        fma4v(__int_as_float(pp1.w), bf2f4(u3), av);
        i += 16;
    }
    if (i + 8 <= e) {
        int4 pp0 = *(const int4*)(pair + i + 2*g);
        uint2 u0 = hb[(size_t)pp0.x * 16 + q];
        uint2 u1 = hb[(size_t)pp0.z * 16 + q];
        fma4v(__int_as_float(pp0.y), bf2f4(u0), av);
        fma4v(__int_as_float(pp0.w), bf2f4(u1), av);
        i += 8;
    }
    if (i + 4 <= e) {
        int2 p0 = pair[i + g];
        uint2 u0 = hb[(size_t)p0.x * 16 + q];
        fma4v(__int_as_float(p0.y), bf2f4(u0), av);
        i += 4;
    }
    if (i < e) {
        int idx = i + g;
        int2 pD = pair[(idx < e) ? idx : (e - 1)];
        float vD = (idx < e) ? __int_as_float(pD.y) : 0.0f;
        uint2 uD = hb[(size_t)pD.x * 16 + q];
        fma4v(vD, bf2f4(uD), av);
    }
    av.x += __shfl_xor(av.x, 32, 64);
    av.y += __shfl_xor(av.y, 32, 64);
    av.z += __shfl_xor(av.z, 32, 64);
    av.w += __shfl_xor(av.w, 32, 64);
    av.x += __shfl_xor(av.x, 16, 64);
    av.y += __shfl_xor(av.y, 16, 64);
    av.z += __shfl_xor(av.z, 16, 64);
    av.w += __shfl_xor(av.w, 16, 64);
    return av;
}

// ---------------------------------------------------------------------------
// spmm layer: hn = bf16(A * hb)
// ---------------------------------------------------------------------------
__global__ void spmm_kernel(const int* __restrict__ row_start,
                            const int* __restrict__ row_cnt,
                            const int2* __restrict__ pair,
                            const uint2* __restrict__ hb,
                            uint2* __restrict__ hn) {
    int wid  = (int)(((size_t)blockIdx.x * blockDim.x + threadIdx.x) >> 6);
    int lane = threadIdx.x & 63;
    int g = lane >> 4, q = lane & 15;
    if (wid >= N_NODES) return;
    int s = row_start[wid];
    int e = s + row_cnt[wid];

    float4 av = gather_row(s, e, g, q, pair, hb);

    if (lane < 16)
        hn[(size_t)wid * 16 + q] = f42bf(av);
}

// ---------------------------------------------------------------------------
// fused final+dot: one wave per query. fin = 0.25*(ego + hA + hB + A*hB).
// ---------------------------------------------------------------------------
__device__ __forceinline__ float4 fin_row(int row, int g, int q, int lane,
                                          const int* __restrict__ row_start,
                                          const int* __restrict__ row_cnt,
                                          const int2* __restrict__ pair,
                                          const uint2* __restrict__ hA,
                                          const uint2* __restrict__ hB,
                                          const float4* __restrict__ ue4,
                                          const float4* __restrict__ ie4) {
    int s = row_start[row];
    int e = s + row_cnt[row];
    float4 av = gather_row(s, e, g, q, pair, hB);
    float4 f = make_float4(0.f, 0.f, 0.f, 0.f);
    if (lane < 16) {
        size_t o = (size_t)row * 16 + q;
        float4 ego = (row < NUM_USERS)
                   ? ue4[(size_t)row * 16 + q]
                   : ie4[(size_t)(row - NUM_USERS) * 16 + q];
        float4 a1 = bf2f4(hA[o]);
        float4 a2 = bf2f4(hB[o]);
        f.x = 0.25f * (ego.x + a1.x + a2.x + av.x);
        f.y = 0.25f * (ego.y + a1.y + a2.y + av.y);
        f.z = 0.25f * (ego.z + a1.z + a2.z + av.z);
        f.w = 0.25f * (ego.w + a1.w + a2.w + av.w);
    }
    return f;
}

__global__ void score_kernel(const int* __restrict__ row_start,
                             const int* __restrict__ row_cnt,
                             const int2* __restrict__ pair,
                             const uint2* __restrict__ hA,
                             const uint2* __restrict__ hB,
                             const float4* __restrict__ ue4,
                             const float4* __restrict__ ie4,
                             const int* __restrict__ users,
                             const int* __restrict__ items,
                             float* __restrict__ out) {
    int qid  = (int)(((size_t)blockIdx.x * blockDim.x + threadIdx.x) >> 6);
    int lane = threadIdx.x & 63;
    int g = lane >> 4, q = lane & 15;
    if (qid >= N_QUERY) return;

    int urow = users[qid];
    int irow = NUM_USERS + items[qid];

    float4 fu = fin_row(urow, g, q, lane, row_start, row_cnt, pair, hA, hB, ue4, ie4);
    float4 fi = fin_row(irow, g, q, lane, row_start, row_cnt, pair, hA, hB, ue4, ie4);

    float p = fu.x * fi.x + fu.y * fi.y + fu.z * fi.z + fu.w * fi.w;
    p += __shfl_xor(p, 8, 64);
    p += __shfl_xor(p, 4, 64);
    p += __shfl_xor(p, 2, 64);
    p += __shfl_xor(p, 1, 64);

    if (lane == 0)
        out[qid] = p;
}

// ---------------------------------------------------------------------------
extern "C" void kernel_launch(void* const* d_in, const int* in_sizes, int n_in,
                              void* d_out, int out_size, void* d_ws, size_t ws_size,
                              hipStream_t stream) {
    const int*   users = (const int*)  d_in[0];
    const int*   items = (const int*)  d_in[1];
    const float* ue    = (const float*)d_in[2];
    const float* ie    = (const float*)d_in[3];
    const int*   rows  = (const int*)  d_in[4];
    const int*   cols  = (const int*)  d_in[5];
    const float* vals  = (const float*)d_in[6];
    float*       out   = (float*)d_out;

    const size_t REC_N = (size_t)NBUCKET * BUCKET_CAP;   // 5,242,880

    // workspace layout (~155 MB):
    //   ego_bf | hA_bf | hB_bf | rec | pair | recRl | ints
    uint2* ego_bf = (uint2*)d_ws;                        // 19.2 MB
    uint2* hA_bf  = ego_bf + NODE_FLOAT4;                // 19.2 MB
    uint2* hB_bf  = hA_bf + NODE_FLOAT4;                 // 19.2 MB
    int2*  rec    = (int2*)(hB_bf + NODE_FLOAT4);        // 41.9 MB
    int2*  pair   = rec + REC_N;                         // 41.9 MB
    unsigned short* recRl = (unsigned short*)(pair + REC_N);  // 10.5 MB

    int* row_start = (int*)(recRl + REC_N);              // 150,016 i
    int* row_cnt   = row_start + 150016;                 // 150,016 i
    int* gcur      = row_cnt + 150016;                   // 256 i

    (void)hipMemsetAsync(gcur, 0, NBUCKET * sizeof(int), stream);

    bin_kernel<<<BIN_BLOCKS, BIN_THREADS, 0, stream>>>(rows, cols, vals, gcur,
                                                       rec, recRl);
    csr_kernel<<<NBUCKET, CSR_THREADS, 0, stream>>>(rec, recRl, gcur,
        row_start, row_cnt, pair, (const float4*)ue, (const float4*)ie, ego_bf);

    int spmm_blocks = (N_NODES * 64 + 255) / 256;
    spmm_kernel<<<spmm_blocks, 256, 0, stream>>>(row_start, row_cnt, pair, ego_bf, hA_bf);
    spmm_kernel<<<spmm_blocks, 256, 0, stream>>>(row_start, row_cnt, pair, hA_bf, hB_bf);

    int score_blocks = (N_QUERY * 64 + 255) / 256;       // 4096
    score_kernel<<<score_blocks, 256, 0, stream>>>(row_start, row_cnt, pair,
        hA_bf, hB_bf, (const float4*)ue, (const float4*)ie, users, items, out);
}